// Round 12
// baseline (191.523 us; speedup 1.0000x reference)
//
#include <hip/hip_runtime.h>
#include <hip/hip_bf16.h>
#include <math.h>

// Problem constants
#define BB 4
#define SS 2048
#define DD 256
#define HH 8
#define HSZ 32

typedef __attribute__((ext_vector_type(8))) short short8;   // 8 bf16 (4 VGPRs)
typedef __attribute__((ext_vector_type(4))) float f32x4;    // MFMA C/D frag

// Async global->LDS DMA, 16B per lane. LDS dest = wave-uniform base + lane*16;
// global src per-lane. Builtin (not asm) so compiler vmcnt bookkeeping sees it.
__device__ __forceinline__ void gload_lds16(const void* g, void* l) {
    __builtin_amdgcn_global_load_lds((const unsigned int*)g, (unsigned int*)l,
                                     16, 0, 0);
}

// Raw hardware exp2: one v_exp_f32 instead of OCML's ~8-op wrapped sequence.
__device__ __forceinline__ float exp2_hw(float x) {
    float r;
    asm("v_exp_f32 %0, %1" : "=v"(r) : "v"(x));
    return r;
}

// One-instruction bf16 pair pack: D = (a>>16) | (b & 0xffff0000)
__device__ __forceinline__ unsigned int perm_pack(float a, float b, unsigned int sel) {
    unsigned int r;
    asm("v_perm_b32 %0, %1, %2, %3"
        : "=v"(r)
        : "v"(__float_as_uint(b)), "v"(__float_as_uint(a)), "s"(sel));
    return r;
}

__device__ __forceinline__ float gelu_f(float x) {
    float x3 = x * x * x;
    float z = 0.7978845608028654f * fmaf(0.044715f, x3, x);
    float e = __expf(2.0f * z);
    float t = 1.0f - 2.0f / (e + 1.0f);
    return 0.5f * x * (1.0f + t);
}

__device__ __forceinline__ unsigned short f2bf(float f) {
    unsigned int u = __float_as_uint(f);
    u = (u + 0x7fffu + ((u >> 16) & 1u)) >> 16;
    return (unsigned short)u;
}

// ---------------- Wave-per-token LayerNorm body (no barriers) ----------------
template<bool HASRES>
__device__ __forceinline__ void ln_wave_body(
    int t, int lane,
    const float* __restrict__ x, const float* __restrict__ addin,
    const float* __restrict__ g, const float* __restrict__ bvec,
    float* __restrict__ resid_out, unsigned short* __restrict__ oln_bf)
{
    const int base = t * DD + lane * 4;
    float4 v4 = *(const float4*)&x[base];
    if (HASRES) {
        float4 a4 = *(const float4*)&addin[base];
        v4.x += a4.x; v4.y += a4.y; v4.z += a4.z; v4.w += a4.w;
        *(float4*)&resid_out[base] = v4;
    }
    float s = (v4.x + v4.y) + (v4.z + v4.w);
    #pragma unroll
    for (int o = 1; o < 64; o <<= 1) s += __shfl_xor(s, o);
    float mean = s * (1.0f / 256.0f);
    float dx = v4.x - mean, dy = v4.y - mean, dz = v4.z - mean, dw = v4.w - mean;
    float q = (dx * dx + dy * dy) + (dz * dz + dw * dw);
    #pragma unroll
    for (int o = 1; o < 64; o <<= 1) q += __shfl_xor(q, o);
    float r = rsqrtf(q * (1.0f / 256.0f) + 1e-6f);
    const float4 g4 = *(const float4*)&g[lane * 4];
    const float4 b4 = *(const float4*)&bvec[lane * 4];
    ushort4 o4;
    o4.x = f2bf(dx * r * g4.x + b4.x);
    o4.y = f2bf(dy * r * g4.y + b4.y);
    o4.z = f2bf(dz * r * g4.z + b4.z);
    o4.w = f2bf(dw * r * g4.w + b4.w);
    *(ushort4*)&oln_bf[base] = o4;
}

// ---------------- Fused prep: weight pack (0..1279) + LN1 (1280..3327) + maskf (3328..3335) ----------------
// Weight segments are written in SLAB-PACKED layout: the exact byte image
// the conv/tail LDS slab double-buffers consume, XOR-swizzle baked in:
//   element (och,k) -> slab s=k>>5, u = och*32+(k&31), u ^= ((u>>6)&7)<<3,
//   ushort index = s*8192 + u.
__global__ __launch_bounds__(256) void prep_kernel(
    const float* __restrict__ Wq, const float* __restrict__ Wk,
    const float* __restrict__ Wv, const float* __restrict__ Wo1,
    const float* __restrict__ Wo2, unsigned short* __restrict__ wt,
    const float* __restrict__ x, const float* __restrict__ ln1g,
    const float* __restrict__ ln1b, unsigned short* __restrict__ h_bf,
    const int* __restrict__ mask, float* __restrict__ maskf)
{
    if (blockIdx.x < 1280) {
        const int WCp = 3 * DD * DD;
        const int WMp = DD * DD;
        const float* src; unsigned short* dst; int rel;
        int i = blockIdx.x;
        if (i < 1152) {
            int seg = i / 192; rel = i % 192;
            src = seg == 0 ? Wq : seg == 1 ? Wq + WCp : seg == 2 ? Wk :
                  seg == 3 ? Wk + WCp : seg == 4 ? Wv : Wv + WCp;
            dst = wt + (size_t)seg * WCp;
        } else {
            int j = i - 1152; int seg = j / 64; rel = j % 64;
            src = seg == 0 ? Wo1 : Wo2;
            dst = wt + (size_t)6 * WCp + (size_t)seg * WMp;
        }
        __shared__ unsigned short t[32][33];
        const int tx = threadIdx.x & 31, ty = threadIdx.x >> 5;
        const int r0 = (rel / 8) * 32, c0 = (rel % 8) * 32;
        #pragma unroll
        for (int j = 0; j < 32; j += 8)
            t[ty + j][tx] = f2bf(src[(r0 + ty + j) * 256 + c0 + tx]);
        __syncthreads();
        #pragma unroll
        for (int j = 0; j < 32; j += 8) {
            unsigned int och = (unsigned int)(c0 + ty + j);
            unsigned int k   = (unsigned int)(r0 + tx);
            unsigned int u   = och * 32u + (k & 31u);
            u ^= ((u >> 6) & 7u) << 3;
            dst[(size_t)(k >> 5) * 8192 + u] = t[tx][ty + j];
        }
    } else if (blockIdx.x < 3328) {
        const int wv = threadIdx.x >> 6, lane = threadIdx.x & 63;
        ln_wave_body<false>((blockIdx.x - 1280) * 4 + wv, lane,
                            x, nullptr, ln1g, ln1b, nullptr, h_bf);
    } else {
        const float M_ON  = -8.0f * 1.4426950408889634f;
        const float M_OFF = -1.442695e30f;
        int i = (blockIdx.x - 3328) * 1024 + threadIdx.x * 4;
        int4 m4 = *(const int4*)&mask[i];
        float4 f4;
        f4.x = m4.x ? M_ON : M_OFF;
        f4.y = m4.y ? M_ON : M_OFF;
        f4.z = m4.z ? M_ON : M_OFF;
        f4.w = m4.w ? M_ON : M_OFF;
        *(float4*)&maskf[i] = f4;
    }
}

// ---------------- Fused dual-layer conv3, 32-token tiles, frag-layout outputs ----------------
// Slab-packed contiguous DMA (1KB/call) + rotated pipeline v2 (R9): per iter
//   lgkm(0) -> issue DMA(it+2) -> MFMA(it regs) -> vmcnt wait(it+1) -> ds_read(it+1)
__global__ __launch_bounds__(256, 3) void convdual_kernel(
    const unsigned short* __restrict__ in,
    const unsigned short* __restrict__ W0a, const unsigned short* __restrict__ W0b,
    const unsigned short* __restrict__ W0c,
    const unsigned short* __restrict__ W1a, const unsigned short* __restrict__ W1b,
    const unsigned short* __restrict__ W1c,
    const float* __restrict__ ba, const float* __restrict__ bb,
    const float* __restrict__ bc,
    unsigned short* __restrict__ oQ, unsigned short* __restrict__ oK,
    unsigned short* __restrict__ oV, int S)
{
    constexpr int LDW = 264;
    __shared__ __align__(16) unsigned short stage[36 * LDW];  // 19008B; aliased as inter + frag buffer
    __shared__ __align__(16) unsigned short wbuf[2][8192];    // 32768B slab double-buffer

    unsigned short* const inter = stage;   // alias: layer-1 output (34 rows x LDW)

    const int set = blockIdx.x % 3;
    const int tile = blockIdx.x / 3;
    const unsigned short* W0 = set == 0 ? W0a : (set == 1 ? W0b : W0c);
    const unsigned short* W1 = set == 0 ? W1a : (set == 1 ? W1b : W1c);
    const float* bias         = set == 0 ? ba  : (set == 1 ? bb  : bc);
    unsigned short* outp      = set == 0 ? oQ  : (set == 1 ? oK  : oV);

    const int tid = threadIdx.x;
    const int lane = tid & 63, wv = tid >> 6;
    const int lm = lane & 15, lq = lane >> 4;
    const int tpb = S / 32;
    const int b = tile / tpb;
    const int s0 = (tile % tpb) * 32;
    const int NC = S / 32;
    const int c = s0 >> 5;

    // stage tokens s0-2 .. s0+33 (rows 0..35)
    for (int i = tid; i < 36 * 32; i += 256) {
        int r = i >> 5, c8 = (i & 31) << 3;
        int s = s0 + r - 2;
        int4 val = make_int4(0, 0, 0, 0);
        if (s >= 0 && s < S)
            val = *(const int4*)&in[(size_t)(b * S + s) * 256 + c8];
        *(int4*)&stage[r * LDW + c8] = val;
    }

    const int n0 = wv * 64;

    // ---- weight-DMA addressing: contiguous per call ----
    const int wq = wv * 4096;                       // wave's quarter (bytes)
    const char* w0p = (const char*)W0 + wq + lane * 16;
    const char* w1p = (const char*)W1 + wq + lane * 16;
    char* const wb0 = (char*)wbuf;

    // B-frag ds_read offsets (swizzled), one per nt
    unsigned int boff[4];
    #pragma unroll
    for (int nt = 0; nt < 4; ++nt) {
        unsigned int och = (unsigned int)(n0 + nt * 16 + lm);
        unsigned int R = och * 64u + (unsigned int)lq * 16u;
        boff[nt] = R ^ (((R >> 7) & 7u) << 4);
    }

    __syncthreads();   // input stage visible; vm counters drained

    // ---- layer 1: rows j=0..33, 3 M-tiles, clamped halo on tile 2 ----
    {
        f32x4 acc[3][4];
        #pragma unroll
        for (int mt = 0; mt < 3; ++mt)
            #pragma unroll
            for (int nt = 0; nt < 4; ++nt) acc[mt][nt] = (f32x4){0.f, 0.f, 0.f, 0.f};

        // prologue: slab 0 -> buf0, slab 1 -> buf1
        #pragma unroll
        for (int j = 0; j < 4; ++j) gload_lds16(w0p + j * 1024,         wb0 + wq + j * 1024);
        #pragma unroll
        for (int j = 0; j < 4; ++j) gload_lds16(w0p + 16384 + j * 1024, wb0 + 16384 + wq + j * 1024);

        // A preload for it = 0
        short8 a0c, a1c, a2c;
        {
            const int icc0 = lq * 8;
            int r20 = 32 + lm; r20 = r20 > 35 ? 35 : r20;
            a0c = *(const short8*)&stage[lm * LDW + icc0];
            a1c = *(const short8*)&stage[(16 + lm) * LDW + icc0];
            a2c = *(const short8*)&stage[r20 * LDW + icc0];
        }

        asm volatile("s_waitcnt vmcnt(4)" ::: "memory");   // slab0 landed
        __builtin_amdgcn_sched_barrier(0);
        short8 bfc[4];
        #pragma unroll
        for (int nt = 0; nt < 4; ++nt)
            bfc[nt] = *(const short8*)(wb0 + boff[nt]);

        #pragma unroll
        for (int it = 0; it < 24; ++it) {
            asm volatile("s_waitcnt lgkmcnt(0)" ::: "memory");  // prior buf reads in regs
            __builtin_amdgcn_sched_barrier(0);
            if (it + 2 < 24) {   // issue slab it+2 into the buffer just consumed
                char* ld = wb0 + ((it & 1) << 14) + wq;
                const int soff = (it + 2) * 16384;
                #pragma unroll
                for (int j = 0; j < 4; ++j)
                    gload_lds16(w0p + soff + j * 1024, ld + j * 1024);
            }
            __builtin_amdgcn_sched_barrier(0);

            __builtin_amdgcn_s_setprio(1);
            #pragma unroll
            for (int nt = 0; nt < 4; ++nt) {
                acc[0][nt] = __builtin_amdgcn_mfma_f32_16x16x32_bf16(a0c, bfc[nt], acc[0][nt], 0, 0, 0);
                acc[1][nt] = __builtin_amdgcn_mfma_f32_16x16x32_bf16(a1c, bfc[nt], acc[1][nt], 0, 0, 0);
                acc[2][nt] = __builtin_amdgcn_mfma_f32_16x16x32_bf16(a2c, bfc[nt], acc[2][nt], 0, 0, 0);
            }
            __builtin_amdgcn_s_setprio(0);
            __builtin_amdgcn_sched_barrier(0);

            if (it + 1 < 24) {
                if (it + 2 < 24) { asm volatile("s_waitcnt vmcnt(4)" ::: "memory"); }
                else             { asm volatile("s_waitcnt vmcnt(0)" ::: "memory"); }
                __builtin_amdgcn_sched_barrier(0);
                const char* wb = wb0 + (((it + 1) & 1) << 14);
                #pragma unroll
                for (int nt = 0; nt < 4; ++nt)
                    bfc[nt] = *(const short8*)(wb + boff[nt]);
                const int kk = (it + 1) >> 3;
                const int icc = ((it + 1) & 7) * 32 + lq * 8;
                int r2 = kk + 32 + lm; r2 = r2 > 35 ? 35 : r2;  // clamped rows feed discarded outputs only
                a0c = *(const short8*)&stage[(kk + lm) * LDW + icc];
                a1c = *(const short8*)&stage[(kk + 16 + lm) * LDW + icc];
                a2c = *(const short8*)&stage[r2 * LDW + icc];
            }
        }

        __syncthreads();   // all waves done reading stage; safe to alias inter onto it

        // issue layer-2 slab 0/1 now; epilogue VALU below covers the DMA latency
        #pragma unroll
        for (int j = 0; j < 4; ++j) gload_lds16(w1p + j * 1024,         wb0 + wq + j * 1024);
        #pragma unroll
        for (int j = 0; j < 4; ++j) gload_lds16(w1p + 16384 + j * 1024, wb0 + 16384 + wq + j * 1024);

        #pragma unroll
        for (int mt = 0; mt < 3; ++mt)
            #pragma unroll
            for (int nt = 0; nt < 4; ++nt) {
                int ch = n0 + nt * 16 + lm;
                float bv = bias[ch];
                #pragma unroll
                for (int r = 0; r < 4; ++r) {
                    int j = mt * 16 + lq * 4 + r;
                    if (j < 34) {
                        int token = s0 - 1 + j;
                        unsigned short v = (token >= 0 && token < S)
                            ? f2bf(gelu_f(acc[mt][nt][r] + bv)) : (unsigned short)0;
                        inter[j * LDW + ch] = v;
                    }
                }
            }
    }
    __syncthreads();   // inter visible; slabs drained by the barrier's vm drain

    // ---- layer 2: rows m=0..31, 2 M-tiles, same rotated pipeline ----
    f32x4 acc2[2][4];
    #pragma unroll
    for (int mt = 0; mt < 2; ++mt)
        #pragma unroll
        for (int nt = 0; nt < 4; ++nt) acc2[mt][nt] = (f32x4){0.f, 0.f, 0.f, 0.f};
    {
        char* const wb0 = (char*)wbuf;
        // A preload for it = 0
        short8 a0c, a1c;
        {
            const int icc0 = lq * 8;
            a0c = *(const short8*)&inter[lm * LDW + icc0];
            a1c = *(const short8*)&inter[(16 + lm) * LDW + icc0];
        }

        asm volatile("s_waitcnt vmcnt(4)" ::: "memory");
        __builtin_amdgcn_sched_barrier(0);
        short8 bfc[4];
        #pragma unroll
        for (int nt = 0; nt < 4; ++nt)
            bfc[nt] = *(const short8*)(wb0 + boff[nt]);

        #pragma unroll
        for (int it = 0; it < 24; ++it) {
            asm volatile("s_waitcnt lgkmcnt(0)" ::: "memory");
            __builtin_amdgcn_sched_barrier(0);
            if (it + 2 < 24) {
                char* ld = wb0 + ((it & 1) << 14) + wq;
                const int soff = (it + 2) * 16384;
                #pragma unroll
                for (int j = 0; j < 4; ++j)
                    gload_lds16(w1p + soff + j * 1024, ld + j * 1024);
            }
            __builtin_amdgcn_sched_barrier(0);

            __builtin_amdgcn_s_setprio(1);
            #pragma unroll
            for (int nt = 0; nt < 4; ++nt) {
                acc2[0][nt] = __builtin_amdgcn_mfma_f32_16x16x32_bf16(a0c, bfc[nt], acc2[0][nt], 0, 0, 0);
                acc2[1][nt] = __builtin_amdgcn_mfma_f32_16x16x32_bf16(a1c, bfc[nt], acc2[1][nt], 0, 0, 0);
            }
            __builtin_amdgcn_s_setprio(0);
            __builtin_amdgcn_sched_barrier(0);

            if (it + 1 < 24) {
                if (it + 2 < 24) { asm volatile("s_waitcnt vmcnt(4)" ::: "memory"); }
                else             { asm volatile("s_waitcnt vmcnt(0)" ::: "memory"); }
                __builtin_amdgcn_sched_barrier(0);
                const char* wb = wb0 + (((it + 1) & 1) << 14);
                #pragma unroll
                for (int nt = 0; nt < 4; ++nt)
                    bfc[nt] = *(const short8*)(wb + boff[nt]);
                const int kk = (it + 1) >> 3;
                const int icc = ((it + 1) & 7) * 32 + lq * 8;
                a0c = *(const short8*)&inter[(kk + lm) * LDW + icc];
                a1c = *(const short8*)&inter[(kk + 16 + lm) * LDW + icc];
            }
        }
    }

    // ---- epilogue: frag-pack both halves into stage, coalesced writeout ----
    __syncthreads();   // all inter reads done; safe to overwrite stage
    if (set < 2) {
        #pragma unroll
        for (int mt = 0; mt < 2; ++mt)       // mt = half
            #pragma unroll
            for (int nt = 0; nt < 4; ++nt) {
                int o = n0 + nt * 16 + lm;
                int d = o & 31, h = o >> 5;
                float bv = bias[256 + o];
                #pragma unroll
                for (int r = 0; r < 4; ++r) {
                    int t = lq * 4 + r;
                    stage[mt * 4096 + (h * 64 + (d >> 3) * 16 + t) * 8 + (d & 7)] =
                        f2bf(acc2[mt][nt][r] + bv);
                }
            }
        __syncthreads();
        int h = tid >> 5;
        size_t base = ((size_t)(b * 8 + h) * NC + c) * 1024;
        #pragma unroll
        for (int half = 0; half < 2; ++half) {
            int4 v0 = *(const int4*)&stage[half * 4096 + tid * 16];
            int4 v1 = *(const int4*)&stage[half * 4096 + tid * 16 + 8];
            size_t dst = base + half * 512 + (tid & 31) * 16;
            *(int4*)&outp[dst] = v0;
            *(int4*)&outp[dst + 8] = v1;
        }
    } else {
        #pragma unroll
        for (int mt = 0; mt < 2; ++mt)
            #pragma unroll
            for (int nt = 0; nt < 4; ++nt) {
                int o = n0 + nt * 16 + lm;
                int d = o & 31, h = o >> 5;
                float bv = bias[256 + o];
                #pragma unroll
                for (int r = 0; r < 4; ++r) {
                    int t = lq * 4 + r;
                    stage[mt * 4096 +
                          ((h * 2 + (d >> 4)) * 32 + (t >> 3) * 16 + (d & 15)) * 8 + (t & 7)] =
                        f2bf(acc2[mt][nt][r] + bv);
                }
            }
        __syncthreads();
        int h = tid >> 5, dh = (tid >> 4) & 1;
        size_t base = ((size_t)(b * 8 + h) * NC + c) * 1024;
        #pragma unroll
        for (int half = 0; half < 2; ++half) {
            int4 v0 = *(const int4*)&stage[half * 4096 + tid * 16];
            int4 v1 = *(const int4*)&stage[half * 4096 + tid * 16 + 8];
            size_t dst = base + dh * 512 + half * 256 + (tid & 15) * 16;
            *(int4*)&outp[dst] = v0;
            *(int4*)&outp[dst + 8] = v1;
        }
    }
}

// ---------------- Fused tail: LN2 + MLP1(gelu) + MLP2 + residual ----------------
// Slab-packed contiguous DMA streaming; rotated pipeline v2 as in convdual.
__global__ __launch_bounds__(256, 2) void tail_kernel(
    const float* __restrict__ x, const float* __restrict__ attn,
    const float* __restrict__ g2, const float* __restrict__ b2,
    const unsigned short* __restrict__ W1, const float* __restrict__ bo1,
    const unsigned short* __restrict__ W2, const float* __restrict__ bo2,
    float* __restrict__ out, int S)
{
    constexpr int LDW = 264;
    __shared__ __align__(16) unsigned short h_lds[16 * LDW];
    __shared__ __align__(16) unsigned short h2_lds[16 * LDW];
    __shared__ __align__(16) float resid_lds[16][DD];
    __shared__ __align__(16) unsigned short wbuf[2][8192];    // 32KB slab dbuf

    const int tid = threadIdx.x;
    const int lane = tid & 63, wv = tid >> 6;
    const int lm = lane & 15, lq = lane >> 4;
    const int t0 = blockIdx.x * 16;
    const int n0 = wv * 64;

    const int wq = wv * 4096;
    const char* w1p = (const char*)W1 + wq + lane * 16;
    const char* w2p = (const char*)W2 + wq + lane * 16;
    char* const wb0 = (char*)wbuf;

    unsigned int boff[4];
    #pragma unroll
    for (int nt = 0; nt < 4; ++nt) {
        unsigned int och = (unsigned int)(n0 + nt * 16 + lm);
        unsigned int R = och * 64u + (unsigned int)lq * 16u;
        boff[nt] = R ^ (((R >> 7) & 7u) << 4);
    }

    // issue W1 slab 0/1 now; LN2 compute below covers the latency
    #pragma unroll
    for (int j = 0; j < 4; ++j) gload_lds16(w1p + j * 1024,         wb0 + wq + j * 1024);
    #pragma unroll
    for (int j = 0; j < 4; ++j) gload_lds16(w1p + 16384 + j * 1024, wb0 + 16384 + wq + j * 1024);

    #pragma unroll
    for (int j = 0; j < 4; ++j) {
        int t = wv * 4 + j;
        int base = (t0 + t) * DD + lane * 4;
        float4 v4 = *(const float4*)&x[base];
        float4 a4 = *(const float4*)&attn[base];
        v4.x += a4.x; v4.y += a4.y; v4.z += a4.z; v4.w += a4.w;
        *(float4*)&resid_lds[t][lane * 4] = v4;
        float s = (v4.x + v4.y) + (v4.z + v4.w);
        #pragma unroll
        for (int o = 1; o < 64; o <<= 1) s += __shfl_xor(s, o);
        float mean = s * (1.0f / 256.0f);
        float dx = v4.x - mean, dy = v4.y - mean, dz = v4.z - mean, dw = v4.w - mean;
        float q = (dx * dx + dy * dy) + (dz * dz + dw * dw);
        #pragma unroll
        for (int o = 1; o < 64; o <<= 1) q += __shfl_xor(q, o);
        float r = rsqrtf(q * (1.0f / 256.0f) + 1e-6f);
        const float4 g4 = *(const float4*)&g2[lane * 4];
        const float4 b4 = *(const float4*)&b2[lane * 4];
        ushort4 o4;
        o4.x = f2bf(dx * r * g4.x + b4.x);
        o4.y = f2bf(dy * r * g4.y + b4.y);
        o4.z = f2bf(dz * r * g4.z + b4.z);
        o4.w = f2bf(dw * r * g4.w + b4.w);
        *(ushort4*)&h_lds[t * LDW + lane * 4] = o4;
    }
    __syncthreads();

    {
        f32x4 acc[4];
        #pragma unroll
        for (int nt = 0; nt < 4; ++nt) acc[nt] = (f32x4){0.f, 0.f, 0.f, 0.f};

        short8 a0c = *(const short8*)&h_lds[lm * LDW + lq * 8];
        asm volatile("s_waitcnt vmcnt(4)" ::: "memory");
        __builtin_amdgcn_sched_barrier(0);
        short8 bfc[4];
        #pragma unroll
        for (int nt = 0; nt < 4; ++nt)
            bfc[nt] = *(const short8*)(wb0 + boff[nt]);

        #pragma unroll
        for (int it = 0; it < 8; ++it) {
            asm volatile("s_waitcnt lgkmcnt(0)" ::: "memory");
            __builtin_amdgcn_sched_barrier(0);
            if (it + 2 < 8) {
                char* ld = wb0 + ((it & 1) << 14) + wq;
                const int soff = (it + 2) * 16384;
                #pragma unroll
                for (int j = 0; j < 4; ++j)
                    gload_lds16(w1p + soff + j * 1024, ld + j * 1024);
            }
            __builtin_amdgcn_sched_barrier(0);

            __builtin_amdgcn_s_setprio(1);
            #pragma unroll
            for (int nt = 0; nt < 4; ++nt)
                acc[nt] = __builtin_amdgcn_mfma_f32_16x16x32_bf16(a0c, bfc[nt], acc[nt], 0, 0, 0);
            __builtin_amdgcn_s_setprio(0);
            __builtin_amdgcn_sched_barrier(0);

            if (it + 1 < 8) {
                if (it + 2 < 8) { asm volatile("s_waitcnt vmcnt(4)" ::: "memory"); }
                else            { asm volatile("s_waitcnt vmcnt(0)" ::: "memory"); }
                __builtin_amdgcn_sched_barrier(0);
                const char* wb = wb0 + (((it + 1) & 1) << 14);
                #pragma unroll
                for (int nt = 0; nt < 4; ++nt)
                    bfc[nt] = *(const short8*)(wb + boff[nt]);
                a0c = *(const short8*)&h_lds[lm * LDW + (it + 1) * 32 + lq * 8];
            }
        }

        // issue W2 slab 0/1; epilogue VALU below covers the latency
        asm volatile("s_waitcnt lgkmcnt(0)" ::: "memory");
        __builtin_amdgcn_sched_barrier(0);
        #pragma unroll
        for (int j = 0; j < 4; ++j) gload_lds16(w2p + j * 1024,         wb0 + wq + j * 1024);
        #pragma unroll
        for (int j = 0; j < 4; ++j) gload_lds16(w2p + 16384 + j * 1024, wb0 + 16384 + wq + j * 1024);

        #pragma unroll
        for (int nt = 0; nt < 4; ++nt) {
            int ch = n0 + nt * 16 + lm;
            float bv = bo1[ch];
            #pragma unroll
            for (int r = 0; r < 4; ++r) {
                int tok = lq * 4 + r;
                h2_lds[tok * LDW + ch] = f2bf(gelu_f(acc[nt][r] + bv));
            }
        }
    }
    __syncthreads();

    {
        f32x4 acc[4];
        #pragma unroll
        for (int nt = 0; nt < 4; ++nt) acc[nt] = (f32x4){0.f, 0.f, 0.f, 0.f};

        short8 a0c = *(const short8*)&h2_lds[lm * LDW + lq * 8];
        asm volatile("s_waitcnt vmcnt(4)" ::: "memory");
        __builtin_amdgcn_sched_barrier(0);
        short8 bfc[4];
        #pragma unroll
        for (int nt = 0; nt < 4; ++nt)
            bfc[nt] = *(const short8*)(wb0 + boff[nt]);

        #pragma unroll
        for (int it = 0; it < 8; ++it) {
            asm volatile("s_waitcnt lgkmcnt(0)" ::: "memory");
            __builtin_amdgcn_sched_barrier(0);
            if (it + 2 < 8) {
                char* ld = wb0 + ((it & 1) << 14) + wq;
                const int soff = (it + 2) * 16384;
                #pragma unroll
                for (int j = 0; j < 4; ++j)
                    gload_lds16(w2p + soff + j * 1024, ld + j * 1024);
            }
            __builtin_amdgcn_sched_barrier(0);

            __builtin_amdgcn_s_setprio(1);
            #pragma unroll
            for (int nt = 0; nt < 4; ++nt)
                acc[nt] = __builtin_amdgcn_mfma_f32_16x16x32_bf16(a0c, bfc[nt], acc[nt], 0, 0, 0);
            __builtin_amdgcn_s_setprio(0);
            __builtin_amdgcn_sched_barrier(0);

            if (it + 1 < 8) {
                if (it + 2 < 8) { asm volatile("s_waitcnt vmcnt(4)" ::: "memory"); }
                else            { asm volatile("s_waitcnt vmcnt(0)" ::: "memory"); }
                __builtin_amdgcn_sched_barrier(0);
                const char* wb = wb0 + (((it + 1) & 1) << 14);
                #pragma unroll
                for (int nt = 0; nt < 4; ++nt)
                    bfc[nt] = *(const short8*)(wb + boff[nt]);
                a0c = *(const short8*)&h2_lds[lm * LDW + (it + 1) * 32 + lq * 8];
            }
        }
        #pragma unroll
        for (int nt = 0; nt < 4; ++nt) {
            int ch = n0 + nt * 16 + lm;
            float bv = bo2[ch];
            #pragma unroll
            for (int r = 0; r < 4; ++r) {
                int tok = lq * 4 + r;
                out[(size_t)(t0 + tok) * DD + ch] = acc[nt][r] + bv + resid_lds[tok][ch];
            }
        }
    }
}

// ---------------- MFMA flash attention v12: 4 Q-frags per wave (quarter K/V traffic) ----------------
// R11 confirmed the L2-traffic model (half traffic -> -20% dur, occupancy halving
// harmless). v12 rides it once more: each wave owns 64 q-rows (two full
// frag-packed Q chunks = 4 fragments), amortizing every K/V chunk over
// 8 QK + 12 PV MFMAs and 32 exps. Grid = BB*H*(S/256) = 256 blocks = 1 wave/SIMD;
// latency hiding now comes from the 4 independent per-qfrag streams (ILP).
__global__ __launch_bounds__(256, 1) void attn_mfma_kernel(
    const unsigned short* __restrict__ Qf, const unsigned short* __restrict__ Kf,
    const unsigned short* __restrict__ Vf, const float* __restrict__ maskf,
    float* __restrict__ Out, int S, int H)
{
    constexpr int LDP = 40;
    __shared__ __align__(16) unsigned short p_lds[4][4][16 * LDP];  // wave x qfrag

    const int bh = ((blockIdx.x & 7) << 2) | ((blockIdx.x >> 3) & 3);  // XCD locality
    const int qt = (blockIdx.x >> 5) * 256;
    const int b = bh / H;
    const int tid = threadIdx.x;
    const int lane = tid & 63, wv = tid >> 6;
    const int lm = lane & 15, lq = lane >> 4;
    const int q0 = qt + wv * 64;            // wave owns 64 q-rows
    const int NC = S / 32;                  // 64, even

    const size_t base = (size_t)bh * NC * 1024;
    const unsigned short* qp = &Qf[base + (size_t)(q0 >> 5) * 1024 + lane * 8];
    short8 qf[4];
    qf[0] = *(const short8*)(qp);            // rows q0   .. q0+15
    qf[1] = *(const short8*)(qp + 512);      // rows q0+16.. q0+31
    qf[2] = *(const short8*)(qp + 1024);     // rows q0+32.. q0+47
    qf[3] = *(const short8*)(qp + 1536);     // rows q0+48.. q0+63
    const unsigned short* kp = Kf + base + lane * 8;
    const unsigned short* vp = Vf + base + lane * 8;

    short8 ones;
    #pragma unroll
    for (int j = 0; j < 8; ++j) ones[j] = (short)0x3F80;  // bf16 1.0

    f32x4 o0[4], o1[4], lacc[4];
    #pragma unroll
    for (int qn = 0; qn < 4; ++qn) {
        o0[qn] = (f32x4){0.f, 0.f, 0.f, 0.f};
        o1[qn] = (f32x4){0.f, 0.f, 0.f, 0.f};
        lacc[qn] = (f32x4){0.f, 0.f, 0.f, 0.f};
    }
    const f32x4 zf = {0.f, 0.f, 0.f, 0.f};

    const float scale2 = 0.17677669529663687f * 1.4426950408889634f;
    const unsigned int psel = 0x07060302u;   // v_perm selector, lives in SGPR
    const float* mp0 = maskf + b * S + lq * 4;
    const float* mp1 = mp0 + 16;

    const int pst = lm * LDP + lq * 4;
    const int prd = lm * LDP + lq * 8;

    // full chunk body: QK for all 4 qfrags, softmax numerators, PV
    auto chunk_body = [&](short8 k0, short8 k1, short8 v0, short8 v1, int c) {
        f32x4 s0[4], s1[4];
        #pragma unroll
        for (int qn = 0; qn < 4; ++qn) {
            s0[qn] = __builtin_amdgcn_mfma_f32_16x16x32_bf16(k0, qf[qn], zf, 0, 0, 0);
            s1[qn] = __builtin_amdgcn_mfma_f32_16x16x32_bf16(k1, qf[qn], zf, 0, 0, 0);
        }
        float4 mf0 = *(const float4*)(mp0 + c * 32);
        float4 mf1 = *(const float4*)(mp1 + c * 32);
        #pragma unroll
        for (int qn = 0; qn < 4; ++qn) {
            float p[8];
            p[0] = exp2_hw(fmaf(s0[qn][0], scale2, mf0.x));
            p[1] = exp2_hw(fmaf(s0[qn][1], scale2, mf0.y));
            p[2] = exp2_hw(fmaf(s0[qn][2], scale2, mf0.z));
            p[3] = exp2_hw(fmaf(s0[qn][3], scale2, mf0.w));
            p[4] = exp2_hw(fmaf(s1[qn][0], scale2, mf1.x));
            p[5] = exp2_hw(fmaf(s1[qn][1], scale2, mf1.y));
            p[6] = exp2_hw(fmaf(s1[qn][2], scale2, mf1.z));
            p[7] = exp2_hw(fmaf(s1[qn][3], scale2, mf1.w));
            uint2 w0, w1;
            w0.x = perm_pack(p[0], p[1], psel); w0.y = perm_pack(p[2], p[3], psel);
            w1.x = perm_pack(p[4], p[5], psel); w1.y = perm_pack(p[6], p[7], psel);
            *(uint2*)&p_lds[wv][qn][pst] = w0;
            *(uint2*)&p_lds[wv][qn][pst + 16] = w1;
        }
        #pragma unroll
        for (int qn = 0; qn < 4; ++qn) {
            short8 pA = *(const short8*)&p_lds[wv][qn][prd];  // wave-private, no barrier
            lacc[qn] = __builtin_amdgcn_mfma_f32_16x16x32_bf16(pA, ones, lacc[qn], 0, 0, 0);
            o0[qn]   = __builtin_amdgcn_mfma_f32_16x16x32_bf16(pA, v0, o0[qn], 0, 0, 0);
            o1[qn]   = __builtin_amdgcn_mfma_f32_16x16x32_bf16(pA, v1, o1[qn], 0, 0, 0);
        }
    };

    // ping-pong register sets; A holds chunk 0 initially
    short8 kA0 = *(const short8*)(kp);
    short8 kA1 = *(const short8*)(kp + 512);
    short8 vA0 = *(const short8*)(vp);
    short8 vA1 = *(const short8*)(vp + 512);
    short8 kB0, kB1, vB0, vB1;

    for (int c = 0; c < NC; c += 2) {
        // prefetch chunk c+1 into B (NC even -> always valid)
        {
            const unsigned short* kq = kp + (size_t)(c + 1) * 1024;
            const unsigned short* vq = vp + (size_t)(c + 1) * 1024;
            kB0 = *(const short8*)(kq);
            kB1 = *(const short8*)(kq + 512);
            vB0 = *(const short8*)(vq);
            vB1 = *(const short8*)(vq + 512);
        }

        chunk_body(kA0, kA1, vA0, vA1, c);

        // prefetch chunk c+2 into A
        if (c + 2 < NC) {
            const unsigned short* kq = kp + (size_t)(c + 2) * 1024;
            const unsigned short* vq = vp + (size_t)(c + 2) * 1024;
            kA0 = *(const short8*)(kq);
            kA1 = *(const short8*)(kq + 512);
            vA0 = *(const short8*)(vq);
            vA1 = *(const short8*)(vq + 512);
        }

        chunk_body(kB0, kB1, vB0, vB1, c + 1);
    }

    #pragma unroll
    for (int qn = 0; qn < 4; ++qn)
        #pragma unroll
        for (int r = 0; r < 4; ++r) {
            float inv = 1.0f / lacc[qn][r];
            size_t ob = (size_t)(b * S + q0 + qn * 16 + lq * 4 + r) * 256 + (bh % H) * 32;
            Out[ob + lm] = o0[qn][r] * inv;
            Out[ob + 16 + lm] = o1[qn][r] * inv;
        }
}

extern "C" void kernel_launch(void* const* d_in, const int* in_sizes, int n_in,
                              void* d_out, int out_size, void* d_ws, size_t ws_size,
                              hipStream_t stream) {
    (void)in_sizes; (void)n_in; (void)out_size; (void)ws_size;
    const float* x    = (const float*)d_in[0];
    const float* ln1g = (const float*)d_in[1];
    const float* ln1b = (const float*)d_in[2];
    const float* Wq   = (const float*)d_in[3];
    const float* bq   = (const float*)d_in[4];
    const float* Wk   = (const float*)d_in[5];
    const float* bk   = (const float*)d_in[6];
    const float* Wv   = (const float*)d_in[7];
    const float* bv   = (const float*)d_in[8];
    const float* ln2g = (const float*)d_in[9];
    const float* ln2b = (const float*)d_in[10];
    const float* Wo1  = (const float*)d_in[11];
    const float* bo1  = (const float*)d_in[12];
    const float* Wo2  = (const float*)d_in[13];
    const float* bo2  = (const float*)d_in[14];
    const int*   mask = (const int*)d_in[15];
    float* out = (float*)d_out;

    const int S = SS, H = HH;
    const int T = BB * SS;                 // 8192 tokens
    const size_t NE = (size_t)T * DD;      // 2M elements
    float* ws    = (float*)d_ws;
    float* attn  = ws + 0 * NE;
    float* maskf = ws + 1 * NE;
    unsigned short* qf_g  = (unsigned short*)(ws + 2 * NE);   // frag-packed Q
    unsigned short* kf_g  = qf_g + NE;                        // frag-packed K
    unsigned short* h_bf  = kf_g + NE;
    unsigned short* wt    = h_bf + NE;
    const int WC = 3 * DD * DD;            // 196608
    const int WM = DD * DD;
    unsigned short* wtq0 = wt;
    unsigned short* wtq1 = wt + WC;
    unsigned short* wtk0 = wt + 2 * WC;
    unsigned short* wtk1 = wt + 3 * WC;
    unsigned short* wtv0 = wt + 4 * WC;
    unsigned short* wtv1 = wt + 5 * WC;
    unsigned short* wto1 = wt + 6 * WC;
    unsigned short* wto2 = wt + 6 * WC + WM;
    unsigned short* vf_g = wt + 6 * WC + 2 * WM;   // frag-packed V

    // fused: 8 weight slab-packs + LN1 + mask->float
    prep_kernel<<<1280 + T / 4 + 8, 256, 0, stream>>>(
        Wq, Wk, Wv, Wo1, Wo2, wt, x, ln1g, ln1b, h_bf, mask, maskf);

    // fused dual-layer temporal encoders (32-token tiles); frag-packed Q/K/V out
    convdual_kernel<<<(T / 32) * 3, 256, 0, stream>>>(
        h_bf, wtq0, wtk0, wtv0, wtq1, wtk1, wtv1, bq, bk, bv,
        qf_g, kf_g, vf_g, S);

    // barrier-free MFMA attention, 4 q-frags/wave -> attn (fp32)
    attn_mfma_kernel<<<BB * H * (S / 256), 256, 0, stream>>>(qf_g, kf_g, vf_g, maskf, attn, S, H);

    // fused tail: LN2 + MLP1 + GELU + MLP2 + residual -> out
    tail_kernel<<<T / 16, 256, 0, stream>>>(
        x, attn, ln2g, ln2b, wto1, bo1, wto2, bo2, out, S);
}

// Round 13
// 188.775 us; speedup vs baseline: 1.0146x; 1.0146x over previous
//
#include <hip/hip_runtime.h>
#include <hip/hip_bf16.h>
#include <math.h>

// Problem constants
#define BB 4
#define SS 2048
#define DD 256
#define HH 8
#define HSZ 32

typedef __attribute__((ext_vector_type(8))) short short8;   // 8 bf16 (4 VGPRs)
typedef __attribute__((ext_vector_type(4))) float f32x4;    // MFMA C/D frag

// Async global->LDS DMA, 16B per lane. LDS dest = wave-uniform base + lane*16;
// global src per-lane. Builtin (not asm) so compiler vmcnt bookkeeping sees it.
__device__ __forceinline__ void gload_lds16(const void* g, void* l) {
    __builtin_amdgcn_global_load_lds((const unsigned int*)g, (unsigned int*)l,
                                     16, 0, 0);
}

// Raw hardware exp2: one v_exp_f32 instead of OCML's ~8-op wrapped sequence.
__device__ __forceinline__ float exp2_hw(float x) {
    float r;
    asm("v_exp_f32 %0, %1" : "=v"(r) : "v"(x));
    return r;
}

// One-instruction bf16 pair pack: D = (a>>16) | (b & 0xffff0000)
__device__ __forceinline__ unsigned int perm_pack(float a, float b, unsigned int sel) {
    unsigned int r;
    asm("v_perm_b32 %0, %1, %2, %3"
        : "=v"(r)
        : "v"(__float_as_uint(b)), "v"(__float_as_uint(a)), "s"(sel));
    return r;
}

__device__ __forceinline__ float gelu_f(float x) {
    float x3 = x * x * x;
    float z = 0.7978845608028654f * fmaf(0.044715f, x3, x);
    float e = __expf(2.0f * z);
    float t = 1.0f - 2.0f / (e + 1.0f);
    return 0.5f * x * (1.0f + t);
}

__device__ __forceinline__ unsigned short f2bf(float f) {
    unsigned int u = __float_as_uint(f);
    u = (u + 0x7fffu + ((u >> 16) & 1u)) >> 16;
    return (unsigned short)u;
}

// ---------------- Wave-per-token LayerNorm body (no barriers) ----------------
template<bool HASRES>
__device__ __forceinline__ void ln_wave_body(
    int t, int lane,
    const float* __restrict__ x, const float* __restrict__ addin,
    const float* __restrict__ g, const float* __restrict__ bvec,
    float* __restrict__ resid_out, unsigned short* __restrict__ oln_bf)
{
    const int base = t * DD + lane * 4;
    float4 v4 = *(const float4*)&x[base];
    if (HASRES) {
        float4 a4 = *(const float4*)&addin[base];
        v4.x += a4.x; v4.y += a4.y; v4.z += a4.z; v4.w += a4.w;
        *(float4*)&resid_out[base] = v4;
    }
    float s = (v4.x + v4.y) + (v4.z + v4.w);
    #pragma unroll
    for (int o = 1; o < 64; o <<= 1) s += __shfl_xor(s, o);
    float mean = s * (1.0f / 256.0f);
    float dx = v4.x - mean, dy = v4.y - mean, dz = v4.z - mean, dw = v4.w - mean;
    float q = (dx * dx + dy * dy) + (dz * dz + dw * dw);
    #pragma unroll
    for (int o = 1; o < 64; o <<= 1) q += __shfl_xor(q, o);
    float r = rsqrtf(q * (1.0f / 256.0f) + 1e-6f);
    const float4 g4 = *(const float4*)&g[lane * 4];
    const float4 b4 = *(const float4*)&bvec[lane * 4];
    ushort4 o4;
    o4.x = f2bf(dx * r * g4.x + b4.x);
    o4.y = f2bf(dy * r * g4.y + b4.y);
    o4.z = f2bf(dz * r * g4.z + b4.z);
    o4.w = f2bf(dw * r * g4.w + b4.w);
    *(ushort4*)&oln_bf[base] = o4;
}

// ---------------- Fused prep: weight pack (0..1279) + LN1 (1280..3327) + maskf (3328..3335) ----------------
// Weight segments are written in SLAB-PACKED layout: the exact byte image
// the conv/tail LDS slab double-buffers consume, XOR-swizzle baked in:
//   element (och,k) -> slab s=k>>5, u = och*32+(k&31), u ^= ((u>>6)&7)<<3,
//   ushort index = s*8192 + u.
__global__ __launch_bounds__(256) void prep_kernel(
    const float* __restrict__ Wq, const float* __restrict__ Wk,
    const float* __restrict__ Wv, const float* __restrict__ Wo1,
    const float* __restrict__ Wo2, unsigned short* __restrict__ wt,
    const float* __restrict__ x, const float* __restrict__ ln1g,
    const float* __restrict__ ln1b, unsigned short* __restrict__ h_bf,
    const int* __restrict__ mask, float* __restrict__ maskf)
{
    if (blockIdx.x < 1280) {
        const int WCp = 3 * DD * DD;
        const int WMp = DD * DD;
        const float* src; unsigned short* dst; int rel;
        int i = blockIdx.x;
        if (i < 1152) {
            int seg = i / 192; rel = i % 192;
            src = seg == 0 ? Wq : seg == 1 ? Wq + WCp : seg == 2 ? Wk :
                  seg == 3 ? Wk + WCp : seg == 4 ? Wv : Wv + WCp;
            dst = wt + (size_t)seg * WCp;
        } else {
            int j = i - 1152; int seg = j / 64; rel = j % 64;
            src = seg == 0 ? Wo1 : Wo2;
            dst = wt + (size_t)6 * WCp + (size_t)seg * WMp;
        }
        __shared__ unsigned short t[32][33];
        const int tx = threadIdx.x & 31, ty = threadIdx.x >> 5;
        const int r0 = (rel / 8) * 32, c0 = (rel % 8) * 32;
        #pragma unroll
        for (int j = 0; j < 32; j += 8)
            t[ty + j][tx] = f2bf(src[(r0 + ty + j) * 256 + c0 + tx]);
        __syncthreads();
        #pragma unroll
        for (int j = 0; j < 32; j += 8) {
            unsigned int och = (unsigned int)(c0 + ty + j);
            unsigned int k   = (unsigned int)(r0 + tx);
            unsigned int u   = och * 32u + (k & 31u);
            u ^= ((u >> 6) & 7u) << 3;
            dst[(size_t)(k >> 5) * 8192 + u] = t[tx][ty + j];
        }
    } else if (blockIdx.x < 3328) {
        const int wv = threadIdx.x >> 6, lane = threadIdx.x & 63;
        ln_wave_body<false>((blockIdx.x - 1280) * 4 + wv, lane,
                            x, nullptr, ln1g, ln1b, nullptr, h_bf);
    } else {
        const float M_ON  = -8.0f * 1.4426950408889634f;
        const float M_OFF = -1.442695e30f;
        int i = (blockIdx.x - 3328) * 1024 + threadIdx.x * 4;
        int4 m4 = *(const int4*)&mask[i];
        float4 f4;
        f4.x = m4.x ? M_ON : M_OFF;
        f4.y = m4.y ? M_ON : M_OFF;
        f4.z = m4.z ? M_ON : M_OFF;
        f4.w = m4.w ? M_ON : M_OFF;
        *(float4*)&maskf[i] = f4;
    }
}

// ---------------- Fused dual-layer conv3, 32-token tiles, frag-layout outputs ----------------
// Slab-packed contiguous DMA (1KB/call) + rotated pipeline v2 (R9): per iter
//   lgkm(0) -> issue DMA(it+2) -> MFMA(it regs) -> vmcnt wait(it+1) -> ds_read(it+1)
__global__ __launch_bounds__(256, 3) void convdual_kernel(
    const unsigned short* __restrict__ in,
    const unsigned short* __restrict__ W0a, const unsigned short* __restrict__ W0b,
    const unsigned short* __restrict__ W0c,
    const unsigned short* __restrict__ W1a, const unsigned short* __restrict__ W1b,
    const unsigned short* __restrict__ W1c,
    const float* __restrict__ ba, const float* __restrict__ bb,
    const float* __restrict__ bc,
    unsigned short* __restrict__ oQ, unsigned short* __restrict__ oK,
    unsigned short* __restrict__ oV, int S)
{
    constexpr int LDW = 264;
    __shared__ __align__(16) unsigned short stage[36 * LDW];  // 19008B; aliased as inter + frag buffer
    __shared__ __align__(16) unsigned short wbuf[2][8192];    // 32768B slab double-buffer

    unsigned short* const inter = stage;   // alias: layer-1 output (34 rows x LDW)

    const int set = blockIdx.x % 3;
    const int tile = blockIdx.x / 3;
    const unsigned short* W0 = set == 0 ? W0a : (set == 1 ? W0b : W0c);
    const unsigned short* W1 = set == 0 ? W1a : (set == 1 ? W1b : W1c);
    const float* bias         = set == 0 ? ba  : (set == 1 ? bb  : bc);
    unsigned short* outp      = set == 0 ? oQ  : (set == 1 ? oK  : oV);

    const int tid = threadIdx.x;
    const int lane = tid & 63, wv = tid >> 6;
    const int lm = lane & 15, lq = lane >> 4;
    const int tpb = S / 32;
    const int b = tile / tpb;
    const int s0 = (tile % tpb) * 32;
    const int NC = S / 32;
    const int c = s0 >> 5;

    // stage tokens s0-2 .. s0+33 (rows 0..35)
    for (int i = tid; i < 36 * 32; i += 256) {
        int r = i >> 5, c8 = (i & 31) << 3;
        int s = s0 + r - 2;
        int4 val = make_int4(0, 0, 0, 0);
        if (s >= 0 && s < S)
            val = *(const int4*)&in[(size_t)(b * S + s) * 256 + c8];
        *(int4*)&stage[r * LDW + c8] = val;
    }

    const int n0 = wv * 64;

    // ---- weight-DMA addressing: contiguous per call ----
    const int wq = wv * 4096;                       // wave's quarter (bytes)
    const char* w0p = (const char*)W0 + wq + lane * 16;
    const char* w1p = (const char*)W1 + wq + lane * 16;
    char* const wb0 = (char*)wbuf;

    // B-frag ds_read offsets (swizzled), one per nt
    unsigned int boff[4];
    #pragma unroll
    for (int nt = 0; nt < 4; ++nt) {
        unsigned int och = (unsigned int)(n0 + nt * 16 + lm);
        unsigned int R = och * 64u + (unsigned int)lq * 16u;
        boff[nt] = R ^ (((R >> 7) & 7u) << 4);
    }

    __syncthreads();   // input stage visible; vm counters drained

    // ---- layer 1: rows j=0..33, 3 M-tiles, clamped halo on tile 2 ----
    {
        f32x4 acc[3][4];
        #pragma unroll
        for (int mt = 0; mt < 3; ++mt)
            #pragma unroll
            for (int nt = 0; nt < 4; ++nt) acc[mt][nt] = (f32x4){0.f, 0.f, 0.f, 0.f};

        // prologue: slab 0 -> buf0, slab 1 -> buf1
        #pragma unroll
        for (int j = 0; j < 4; ++j) gload_lds16(w0p + j * 1024,         wb0 + wq + j * 1024);
        #pragma unroll
        for (int j = 0; j < 4; ++j) gload_lds16(w0p + 16384 + j * 1024, wb0 + 16384 + wq + j * 1024);

        // A preload for it = 0
        short8 a0c, a1c, a2c;
        {
            const int icc0 = lq * 8;
            int r20 = 32 + lm; r20 = r20 > 35 ? 35 : r20;
            a0c = *(const short8*)&stage[lm * LDW + icc0];
            a1c = *(const short8*)&stage[(16 + lm) * LDW + icc0];
            a2c = *(const short8*)&stage[r20 * LDW + icc0];
        }

        asm volatile("s_waitcnt vmcnt(4)" ::: "memory");   // slab0 landed
        __builtin_amdgcn_sched_barrier(0);
        short8 bfc[4];
        #pragma unroll
        for (int nt = 0; nt < 4; ++nt)
            bfc[nt] = *(const short8*)(wb0 + boff[nt]);

        #pragma unroll
        for (int it = 0; it < 24; ++it) {
            asm volatile("s_waitcnt lgkmcnt(0)" ::: "memory");  // prior buf reads in regs
            __builtin_amdgcn_sched_barrier(0);
            if (it + 2 < 24) {   // issue slab it+2 into the buffer just consumed
                char* ld = wb0 + ((it & 1) << 14) + wq;
                const int soff = (it + 2) * 16384;
                #pragma unroll
                for (int j = 0; j < 4; ++j)
                    gload_lds16(w0p + soff + j * 1024, ld + j * 1024);
            }
            __builtin_amdgcn_sched_barrier(0);

            __builtin_amdgcn_s_setprio(1);
            #pragma unroll
            for (int nt = 0; nt < 4; ++nt) {
                acc[0][nt] = __builtin_amdgcn_mfma_f32_16x16x32_bf16(a0c, bfc[nt], acc[0][nt], 0, 0, 0);
                acc[1][nt] = __builtin_amdgcn_mfma_f32_16x16x32_bf16(a1c, bfc[nt], acc[1][nt], 0, 0, 0);
                acc[2][nt] = __builtin_amdgcn_mfma_f32_16x16x32_bf16(a2c, bfc[nt], acc[2][nt], 0, 0, 0);
            }
            __builtin_amdgcn_s_setprio(0);
            __builtin_amdgcn_sched_barrier(0);

            if (it + 1 < 24) {
                if (it + 2 < 24) { asm volatile("s_waitcnt vmcnt(4)" ::: "memory"); }
                else             { asm volatile("s_waitcnt vmcnt(0)" ::: "memory"); }
                __builtin_amdgcn_sched_barrier(0);
                const char* wb = wb0 + (((it + 1) & 1) << 14);
                #pragma unroll
                for (int nt = 0; nt < 4; ++nt)
                    bfc[nt] = *(const short8*)(wb + boff[nt]);
                const int kk = (it + 1) >> 3;
                const int icc = ((it + 1) & 7) * 32 + lq * 8;
                int r2 = kk + 32 + lm; r2 = r2 > 35 ? 35 : r2;  // clamped rows feed discarded outputs only
                a0c = *(const short8*)&stage[(kk + lm) * LDW + icc];
                a1c = *(const short8*)&stage[(kk + 16 + lm) * LDW + icc];
                a2c = *(const short8*)&stage[r2 * LDW + icc];
            }
        }

        __syncthreads();   // all waves done reading stage; safe to alias inter onto it

        // issue layer-2 slab 0/1 now; epilogue VALU below covers the DMA latency
        #pragma unroll
        for (int j = 0; j < 4; ++j) gload_lds16(w1p + j * 1024,         wb0 + wq + j * 1024);
        #pragma unroll
        for (int j = 0; j < 4; ++j) gload_lds16(w1p + 16384 + j * 1024, wb0 + 16384 + wq + j * 1024);

        #pragma unroll
        for (int mt = 0; mt < 3; ++mt)
            #pragma unroll
            for (int nt = 0; nt < 4; ++nt) {
                int ch = n0 + nt * 16 + lm;
                float bv = bias[ch];
                #pragma unroll
                for (int r = 0; r < 4; ++r) {
                    int j = mt * 16 + lq * 4 + r;
                    if (j < 34) {
                        int token = s0 - 1 + j;
                        unsigned short v = (token >= 0 && token < S)
                            ? f2bf(gelu_f(acc[mt][nt][r] + bv)) : (unsigned short)0;
                        inter[j * LDW + ch] = v;
                    }
                }
            }
    }
    __syncthreads();   // inter visible; slabs drained by the barrier's vm drain

    // ---- layer 2: rows m=0..31, 2 M-tiles, same rotated pipeline ----
    f32x4 acc2[2][4];
    #pragma unroll
    for (int mt = 0; mt < 2; ++mt)
        #pragma unroll
        for (int nt = 0; nt < 4; ++nt) acc2[mt][nt] = (f32x4){0.f, 0.f, 0.f, 0.f};
    {
        char* const wb0 = (char*)wbuf;
        // A preload for it = 0
        short8 a0c, a1c;
        {
            const int icc0 = lq * 8;
            a0c = *(const short8*)&inter[lm * LDW + icc0];
            a1c = *(const short8*)&inter[(16 + lm) * LDW + icc0];
        }

        asm volatile("s_waitcnt vmcnt(4)" ::: "memory");
        __builtin_amdgcn_sched_barrier(0);
        short8 bfc[4];
        #pragma unroll
        for (int nt = 0; nt < 4; ++nt)
            bfc[nt] = *(const short8*)(wb0 + boff[nt]);

        #pragma unroll
        for (int it = 0; it < 24; ++it) {
            asm volatile("s_waitcnt lgkmcnt(0)" ::: "memory");
            __builtin_amdgcn_sched_barrier(0);
            if (it + 2 < 24) {
                char* ld = wb0 + ((it & 1) << 14) + wq;
                const int soff = (it + 2) * 16384;
                #pragma unroll
                for (int j = 0; j < 4; ++j)
                    gload_lds16(w1p + soff + j * 1024, ld + j * 1024);
            }
            __builtin_amdgcn_sched_barrier(0);

            __builtin_amdgcn_s_setprio(1);
            #pragma unroll
            for (int nt = 0; nt < 4; ++nt) {
                acc2[0][nt] = __builtin_amdgcn_mfma_f32_16x16x32_bf16(a0c, bfc[nt], acc2[0][nt], 0, 0, 0);
                acc2[1][nt] = __builtin_amdgcn_mfma_f32_16x16x32_bf16(a1c, bfc[nt], acc2[1][nt], 0, 0, 0);
            }
            __builtin_amdgcn_s_setprio(0);
            __builtin_amdgcn_sched_barrier(0);

            if (it + 1 < 24) {
                if (it + 2 < 24) { asm volatile("s_waitcnt vmcnt(4)" ::: "memory"); }
                else             { asm volatile("s_waitcnt vmcnt(0)" ::: "memory"); }
                __builtin_amdgcn_sched_barrier(0);
                const char* wb = wb0 + (((it + 1) & 1) << 14);
                #pragma unroll
                for (int nt = 0; nt < 4; ++nt)
                    bfc[nt] = *(const short8*)(wb + boff[nt]);
                const int kk = (it + 1) >> 3;
                const int icc = ((it + 1) & 7) * 32 + lq * 8;
                a0c = *(const short8*)&inter[(kk + lm) * LDW + icc];
                a1c = *(const short8*)&inter[(kk + 16 + lm) * LDW + icc];
            }
        }
    }

    // ---- epilogue: frag-pack both halves into stage, coalesced writeout ----
    __syncthreads();   // all inter reads done; safe to overwrite stage
    if (set < 2) {
        #pragma unroll
        for (int mt = 0; mt < 2; ++mt)       // mt = half
            #pragma unroll
            for (int nt = 0; nt < 4; ++nt) {
                int o = n0 + nt * 16 + lm;
                int d = o & 31, h = o >> 5;
                float bv = bias[256 + o];
                #pragma unroll
                for (int r = 0; r < 4; ++r) {
                    int t = lq * 4 + r;
                    stage[mt * 4096 + (h * 64 + (d >> 3) * 16 + t) * 8 + (d & 7)] =
                        f2bf(acc2[mt][nt][r] + bv);
                }
            }
        __syncthreads();
        int h = tid >> 5;
        size_t base = ((size_t)(b * 8 + h) * NC + c) * 1024;
        #pragma unroll
        for (int half = 0; half < 2; ++half) {
            int4 v0 = *(const int4*)&stage[half * 4096 + tid * 16];
            int4 v1 = *(const int4*)&stage[half * 4096 + tid * 16 + 8];
            size_t dst = base + half * 512 + (tid & 31) * 16;
            *(int4*)&outp[dst] = v0;
            *(int4*)&outp[dst + 8] = v1;
        }
    } else {
        #pragma unroll
        for (int mt = 0; mt < 2; ++mt)
            #pragma unroll
            for (int nt = 0; nt < 4; ++nt) {
                int o = n0 + nt * 16 + lm;
                int d = o & 31, h = o >> 5;
                float bv = bias[256 + o];
                #pragma unroll
                for (int r = 0; r < 4; ++r) {
                    int t = lq * 4 + r;
                    stage[mt * 4096 +
                          ((h * 2 + (d >> 4)) * 32 + (t >> 3) * 16 + (d & 15)) * 8 + (t & 7)] =
                        f2bf(acc2[mt][nt][r] + bv);
                }
            }
        __syncthreads();
        int h = tid >> 5, dh = (tid >> 4) & 1;
        size_t base = ((size_t)(b * 8 + h) * NC + c) * 1024;
        #pragma unroll
        for (int half = 0; half < 2; ++half) {
            int4 v0 = *(const int4*)&stage[half * 4096 + tid * 16];
            int4 v1 = *(const int4*)&stage[half * 4096 + tid * 16 + 8];
            size_t dst = base + dh * 512 + half * 256 + (tid & 15) * 16;
            *(int4*)&outp[dst] = v0;
            *(int4*)&outp[dst + 8] = v1;
        }
    }
}

// ---------------- Fused tail: LN2 + MLP1(gelu) + MLP2 + residual ----------------
// Slab-packed contiguous DMA streaming; rotated pipeline v2 as in convdual.
__global__ __launch_bounds__(256, 2) void tail_kernel(
    const float* __restrict__ x, const float* __restrict__ attn,
    const float* __restrict__ g2, const float* __restrict__ b2,
    const unsigned short* __restrict__ W1, const float* __restrict__ bo1,
    const unsigned short* __restrict__ W2, const float* __restrict__ bo2,
    float* __restrict__ out, int S)
{
    constexpr int LDW = 264;
    __shared__ __align__(16) unsigned short h_lds[16 * LDW];
    __shared__ __align__(16) unsigned short h2_lds[16 * LDW];
    __shared__ __align__(16) float resid_lds[16][DD];
    __shared__ __align__(16) unsigned short wbuf[2][8192];    // 32KB slab dbuf

    const int tid = threadIdx.x;
    const int lane = tid & 63, wv = tid >> 6;
    const int lm = lane & 15, lq = lane >> 4;
    const int t0 = blockIdx.x * 16;
    const int n0 = wv * 64;

    const int wq = wv * 4096;
    const char* w1p = (const char*)W1 + wq + lane * 16;
    const char* w2p = (const char*)W2 + wq + lane * 16;
    char* const wb0 = (char*)wbuf;

    unsigned int boff[4];
    #pragma unroll
    for (int nt = 0; nt < 4; ++nt) {
        unsigned int och = (unsigned int)(n0 + nt * 16 + lm);
        unsigned int R = och * 64u + (unsigned int)lq * 16u;
        boff[nt] = R ^ (((R >> 7) & 7u) << 4);
    }

    // issue W1 slab 0/1 now; LN2 compute below covers the latency
    #pragma unroll
    for (int j = 0; j < 4; ++j) gload_lds16(w1p + j * 1024,         wb0 + wq + j * 1024);
    #pragma unroll
    for (int j = 0; j < 4; ++j) gload_lds16(w1p + 16384 + j * 1024, wb0 + 16384 + wq + j * 1024);

    #pragma unroll
    for (int j = 0; j < 4; ++j) {
        int t = wv * 4 + j;
        int base = (t0 + t) * DD + lane * 4;
        float4 v4 = *(const float4*)&x[base];
        float4 a4 = *(const float4*)&attn[base];
        v4.x += a4.x; v4.y += a4.y; v4.z += a4.z; v4.w += a4.w;
        *(float4*)&resid_lds[t][lane * 4] = v4;
        float s = (v4.x + v4.y) + (v4.z + v4.w);
        #pragma unroll
        for (int o = 1; o < 64; o <<= 1) s += __shfl_xor(s, o);
        float mean = s * (1.0f / 256.0f);
        float dx = v4.x - mean, dy = v4.y - mean, dz = v4.z - mean, dw = v4.w - mean;
        float q = (dx * dx + dy * dy) + (dz * dz + dw * dw);
        #pragma unroll
        for (int o = 1; o < 64; o <<= 1) q += __shfl_xor(q, o);
        float r = rsqrtf(q * (1.0f / 256.0f) + 1e-6f);
        const float4 g4 = *(const float4*)&g2[lane * 4];
        const float4 b4 = *(const float4*)&b2[lane * 4];
        ushort4 o4;
        o4.x = f2bf(dx * r * g4.x + b4.x);
        o4.y = f2bf(dy * r * g4.y + b4.y);
        o4.z = f2bf(dz * r * g4.z + b4.z);
        o4.w = f2bf(dw * r * g4.w + b4.w);
        *(ushort4*)&h_lds[t * LDW + lane * 4] = o4;
    }
    __syncthreads();

    {
        f32x4 acc[4];
        #pragma unroll
        for (int nt = 0; nt < 4; ++nt) acc[nt] = (f32x4){0.f, 0.f, 0.f, 0.f};

        short8 a0c = *(const short8*)&h_lds[lm * LDW + lq * 8];
        asm volatile("s_waitcnt vmcnt(4)" ::: "memory");
        __builtin_amdgcn_sched_barrier(0);
        short8 bfc[4];
        #pragma unroll
        for (int nt = 0; nt < 4; ++nt)
            bfc[nt] = *(const short8*)(wb0 + boff[nt]);

        #pragma unroll
        for (int it = 0; it < 8; ++it) {
            asm volatile("s_waitcnt lgkmcnt(0)" ::: "memory");
            __builtin_amdgcn_sched_barrier(0);
            if (it + 2 < 8) {
                char* ld = wb0 + ((it & 1) << 14) + wq;
                const int soff = (it + 2) * 16384;
                #pragma unroll
                for (int j = 0; j < 4; ++j)
                    gload_lds16(w1p + soff + j * 1024, ld + j * 1024);
            }
            __builtin_amdgcn_sched_barrier(0);

            __builtin_amdgcn_s_setprio(1);
            #pragma unroll
            for (int nt = 0; nt < 4; ++nt)
                acc[nt] = __builtin_amdgcn_mfma_f32_16x16x32_bf16(a0c, bfc[nt], acc[nt], 0, 0, 0);
            __builtin_amdgcn_s_setprio(0);
            __builtin_amdgcn_sched_barrier(0);

            if (it + 1 < 8) {
                if (it + 2 < 8) { asm volatile("s_waitcnt vmcnt(4)" ::: "memory"); }
                else            { asm volatile("s_waitcnt vmcnt(0)" ::: "memory"); }
                __builtin_amdgcn_sched_barrier(0);
                const char* wb = wb0 + (((it + 1) & 1) << 14);
                #pragma unroll
                for (int nt = 0; nt < 4; ++nt)
                    bfc[nt] = *(const short8*)(wb + boff[nt]);
                a0c = *(const short8*)&h_lds[lm * LDW + (it + 1) * 32 + lq * 8];
            }
        }

        // issue W2 slab 0/1; epilogue VALU below covers the latency
        asm volatile("s_waitcnt lgkmcnt(0)" ::: "memory");
        __builtin_amdgcn_sched_barrier(0);
        #pragma unroll
        for (int j = 0; j < 4; ++j) gload_lds16(w2p + j * 1024,         wb0 + wq + j * 1024);
        #pragma unroll
        for (int j = 0; j < 4; ++j) gload_lds16(w2p + 16384 + j * 1024, wb0 + 16384 + wq + j * 1024);

        #pragma unroll
        for (int nt = 0; nt < 4; ++nt) {
            int ch = n0 + nt * 16 + lm;
            float bv = bo1[ch];
            #pragma unroll
            for (int r = 0; r < 4; ++r) {
                int tok = lq * 4 + r;
                h2_lds[tok * LDW + ch] = f2bf(gelu_f(acc[nt][r] + bv));
            }
        }
    }
    __syncthreads();

    {
        f32x4 acc[4];
        #pragma unroll
        for (int nt = 0; nt < 4; ++nt) acc[nt] = (f32x4){0.f, 0.f, 0.f, 0.f};

        short8 a0c = *(const short8*)&h2_lds[lm * LDW + lq * 8];
        asm volatile("s_waitcnt vmcnt(4)" ::: "memory");
        __builtin_amdgcn_sched_barrier(0);
        short8 bfc[4];
        #pragma unroll
        for (int nt = 0; nt < 4; ++nt)
            bfc[nt] = *(const short8*)(wb0 + boff[nt]);

        #pragma unroll
        for (int it = 0; it < 8; ++it) {
            asm volatile("s_waitcnt lgkmcnt(0)" ::: "memory");
            __builtin_amdgcn_sched_barrier(0);
            if (it + 2 < 8) {
                char* ld = wb0 + ((it & 1) << 14) + wq;
                const int soff = (it + 2) * 16384;
                #pragma unroll
                for (int j = 0; j < 4; ++j)
                    gload_lds16(w2p + soff + j * 1024, ld + j * 1024);
            }
            __builtin_amdgcn_sched_barrier(0);

            __builtin_amdgcn_s_setprio(1);
            #pragma unroll
            for (int nt = 0; nt < 4; ++nt)
                acc[nt] = __builtin_amdgcn_mfma_f32_16x16x32_bf16(a0c, bfc[nt], acc[nt], 0, 0, 0);
            __builtin_amdgcn_s_setprio(0);
            __builtin_amdgcn_sched_barrier(0);

            if (it + 1 < 8) {
                if (it + 2 < 8) { asm volatile("s_waitcnt vmcnt(4)" ::: "memory"); }
                else            { asm volatile("s_waitcnt vmcnt(0)" ::: "memory"); }
                __builtin_amdgcn_sched_barrier(0);
                const char* wb = wb0 + (((it + 1) & 1) << 14);
                #pragma unroll
                for (int nt = 0; nt < 4; ++nt)
                    bfc[nt] = *(const short8*)(wb + boff[nt]);
                a0c = *(const short8*)&h2_lds[lm * LDW + (it + 1) * 32 + lq * 8];
            }
        }
        #pragma unroll
        for (int nt = 0; nt < 4; ++nt) {
            int ch = n0 + nt * 16 + lm;
            float bv = bo2[ch];
            #pragma unroll
            for (int r = 0; r < 4; ++r) {
                int tok = lq * 4 + r;
                out[(size_t)(t0 + tok) * DD + ch] = acc[nt][r] + bv + resid_lds[tok][ch];
            }
        }
    }
}

// ---------------- MFMA flash attention v13: v11 + block-shared LDS K/V (4x less L2 traffic) ----------------
// R12 falsified "traffic at any occupancy": 1 wave/SIMD lost more to latency than
// quartered traffic gained. v13 keeps v11's 2 waves/SIMD AND cuts traffic 4x:
// the block's 4 waves share one K/V stream staged in LDS. Each wave DMAs one
// 1KB segment of each 4KB chunk (global_load_lds, convdual-proven); two barriers
// per chunk order stage->read->overwrite. Compute math identical to v11
// (2 q-frags/wave, MFMA-accumulated row sums).
__global__ __launch_bounds__(256) void attn_mfma_kernel(
    const unsigned short* __restrict__ Qf, const unsigned short* __restrict__ Kf,
    const unsigned short* __restrict__ Vf, const float* __restrict__ maskf,
    float* __restrict__ Out, int S, int H)
{
    constexpr int LDP = 40;
    __shared__ __align__(16) unsigned short p_lds[4][2][16 * LDP];  // 10240B
    __shared__ __align__(16) unsigned short kvbuf[2][2048];         // 2 slots x 4KB [K0|K1|V0|V1]

    const int bh = ((blockIdx.x & 7) << 2) | ((blockIdx.x >> 3) & 3);  // XCD locality
    const int qt = (blockIdx.x >> 5) * 128;
    const int b = bh / H;
    const int tid = threadIdx.x;
    const int lane = tid & 63, wv = tid >> 6;
    const int lm = lane & 15, lq = lane >> 4;
    const int q0 = qt + wv * 32;            // wave owns 32 q-rows
    const int NC = S / 32;                  // 64

    const size_t base = (size_t)bh * NC * 1024;
    const unsigned short* qp = &Qf[base + (size_t)(q0 >> 5) * 1024 + lane * 8];
    short8 qf0 = *(const short8*)(qp);       // rows q0..q0+15
    short8 qf1 = *(const short8*)(qp + 512); // rows q0+16..q0+31

    // block-shared K/V DMA: wave wv stages segment wv of each chunk
    // seg0 = K frag0 (1KB), seg1 = K frag1, seg2 = V frag0, seg3 = V frag1
    const char* gsrc = (const char*)(wv < 2 ? Kf + base : Vf + base)
                       + (wv & 1) * 1024 + (size_t)lane * 16;
    char* const lb = (char*)kvbuf;
    const int lseg = wv * 1024;

    short8 ones;
    #pragma unroll
    for (int j = 0; j < 8; ++j) ones[j] = (short)0x3F80;  // bf16 1.0

    f32x4 o00 = {0.f, 0.f, 0.f, 0.f}, o01 = {0.f, 0.f, 0.f, 0.f};
    f32x4 o10 = {0.f, 0.f, 0.f, 0.f}, o11 = {0.f, 0.f, 0.f, 0.f};
    f32x4 lacc0 = {0.f, 0.f, 0.f, 0.f}, lacc1 = {0.f, 0.f, 0.f, 0.f};
    const f32x4 zf = {0.f, 0.f, 0.f, 0.f};

    const float scale2 = 0.17677669529663687f * 1.4426950408889634f;
    const unsigned int psel = 0x07060302u;   // v_perm selector, lives in SGPR
    const float* mp0 = maskf + b * S + lq * 4;
    const float* mp1 = mp0 + 16;

    unsigned short* pw0 = p_lds[wv][0];
    unsigned short* pw1 = p_lds[wv][1];
    const int pst = lm * LDP + lq * 4;
    const int prd = lm * LDP + lq * 8;

    // prologue: chunk 0 -> slot 0, chunk 1 -> slot 1 (each wave its segment)
    gload_lds16(gsrc,        lb + lseg);
    gload_lds16(gsrc + 2048, lb + 4096 + lseg);

    for (int c = 0; c < NC; ++c) {
        // own segment of chunk c (and anything older) landed
        asm volatile("s_waitcnt vmcnt(0)" ::: "memory");
        __builtin_amdgcn_sched_barrier(0);
        __syncthreads();                         // ALL segments of chunk c visible

        const char* kb = lb + ((c & 1) << 12);
        short8 k0 = *(const short8*)(kb + (size_t)lane * 16);
        short8 k1 = *(const short8*)(kb + 1024 + (size_t)lane * 16);
        short8 v0 = *(const short8*)(kb + 2048 + (size_t)lane * 16);
        short8 v1 = *(const short8*)(kb + 3072 + (size_t)lane * 16);
        asm volatile("s_waitcnt lgkmcnt(0)" ::: "memory");   // frags in regs
        __builtin_amdgcn_sched_barrier(0);
        __syncthreads();                         // slot free for overwrite

        if (c + 2 < NC)
            gload_lds16(gsrc + (size_t)(c + 2) * 2048, lb + ((c & 1) << 12) + lseg);

        // ---- compute chunk c (identical math to v11) ----
        f32x4 s00 = __builtin_amdgcn_mfma_f32_16x16x32_bf16(k0, qf0, zf, 0, 0, 0);
        f32x4 s01 = __builtin_amdgcn_mfma_f32_16x16x32_bf16(k1, qf0, zf, 0, 0, 0);
        f32x4 s10 = __builtin_amdgcn_mfma_f32_16x16x32_bf16(k0, qf1, zf, 0, 0, 0);
        f32x4 s11 = __builtin_amdgcn_mfma_f32_16x16x32_bf16(k1, qf1, zf, 0, 0, 0);

        float4 mf0 = *(const float4*)(mp0 + c * 32);
        float4 mf1 = *(const float4*)(mp1 + c * 32);

        float p0[8], p1[8];
        p0[0] = exp2_hw(fmaf(s00[0], scale2, mf0.x));
        p0[1] = exp2_hw(fmaf(s00[1], scale2, mf0.y));
        p0[2] = exp2_hw(fmaf(s00[2], scale2, mf0.z));
        p0[3] = exp2_hw(fmaf(s00[3], scale2, mf0.w));
        p0[4] = exp2_hw(fmaf(s01[0], scale2, mf1.x));
        p0[5] = exp2_hw(fmaf(s01[1], scale2, mf1.y));
        p0[6] = exp2_hw(fmaf(s01[2], scale2, mf1.z));
        p0[7] = exp2_hw(fmaf(s01[3], scale2, mf1.w));
        p1[0] = exp2_hw(fmaf(s10[0], scale2, mf0.x));
        p1[1] = exp2_hw(fmaf(s10[1], scale2, mf0.y));
        p1[2] = exp2_hw(fmaf(s10[2], scale2, mf0.z));
        p1[3] = exp2_hw(fmaf(s10[3], scale2, mf0.w));
        p1[4] = exp2_hw(fmaf(s11[0], scale2, mf1.x));
        p1[5] = exp2_hw(fmaf(s11[1], scale2, mf1.y));
        p1[6] = exp2_hw(fmaf(s11[2], scale2, mf1.z));
        p1[7] = exp2_hw(fmaf(s11[3], scale2, mf1.w));

        uint2 w0, w1;
        w0.x = perm_pack(p0[0], p0[1], psel); w0.y = perm_pack(p0[2], p0[3], psel);
        w1.x = perm_pack(p0[4], p0[5], psel); w1.y = perm_pack(p0[6], p0[7], psel);
        *(uint2*)&pw0[pst] = w0;
        *(uint2*)&pw0[pst + 16] = w1;
        w0.x = perm_pack(p1[0], p1[1], psel); w0.y = perm_pack(p1[2], p1[3], psel);
        w1.x = perm_pack(p1[4], p1[5], psel); w1.y = perm_pack(p1[6], p1[7], psel);
        *(uint2*)&pw1[pst] = w0;
        *(uint2*)&pw1[pst + 16] = w1;

        short8 pA0 = *(const short8*)&pw0[prd];   // wave-private, no barrier
        short8 pA1 = *(const short8*)&pw1[prd];

        lacc0 = __builtin_amdgcn_mfma_f32_16x16x32_bf16(pA0, ones, lacc0, 0, 0, 0);
        o00   = __builtin_amdgcn_mfma_f32_16x16x32_bf16(pA0, v0, o00, 0, 0, 0);
        o01   = __builtin_amdgcn_mfma_f32_16x16x32_bf16(pA0, v1, o01, 0, 0, 0);
        lacc1 = __builtin_amdgcn_mfma_f32_16x16x32_bf16(pA1, ones, lacc1, 0, 0, 0);
        o10   = __builtin_amdgcn_mfma_f32_16x16x32_bf16(pA1, v0, o10, 0, 0, 0);
        o11   = __builtin_amdgcn_mfma_f32_16x16x32_bf16(pA1, v1, o11, 0, 0, 0);
    }

    #pragma unroll
    for (int r = 0; r < 4; ++r) {
        float inv0 = 1.0f / lacc0[r];
        size_t ob0 = (size_t)(b * S + q0 + lq * 4 + r) * 256 + (bh % H) * 32;
        Out[ob0 + lm] = o00[r] * inv0;
        Out[ob0 + 16 + lm] = o01[r] * inv0;
        float inv1 = 1.0f / lacc1[r];
        size_t ob1 = (size_t)(b * S + q0 + 16 + lq * 4 + r) * 256 + (bh % H) * 32;
        Out[ob1 + lm] = o10[r] * inv1;
        Out[ob1 + 16 + lm] = o11[r] * inv1;
    }
}

extern "C" void kernel_launch(void* const* d_in, const int* in_sizes, int n_in,
                              void* d_out, int out_size, void* d_ws, size_t ws_size,
                              hipStream_t stream) {
    (void)in_sizes; (void)n_in; (void)out_size; (void)ws_size;
    const float* x    = (const float*)d_in[0];
    const float* ln1g = (const float*)d_in[1];
    const float* ln1b = (const float*)d_in[2];
    const float* Wq   = (const float*)d_in[3];
    const float* bq   = (const float*)d_in[4];
    const float* Wk   = (const float*)d_in[5];
    const float* bk   = (const float*)d_in[6];
    const float* Wv   = (const float*)d_in[7];
    const float* bv   = (const float*)d_in[8];
    const float* ln2g = (const float*)d_in[9];
    const float* ln2b = (const float*)d_in[10];
    const float* Wo1  = (const float*)d_in[11];
    const float* bo1  = (const float*)d_in[12];
    const float* Wo2  = (const float*)d_in[13];
    const float* bo2  = (const float*)d_in[14];
    const int*   mask = (const int*)d_in[15];
    float* out = (float*)d_out;

    const int S = SS, H = HH;
    const int T = BB * SS;                 // 8192 tokens
    const size_t NE = (size_t)T * DD;      // 2M elements
    float* ws    = (float*)d_ws;
    float* attn  = ws + 0 * NE;
    float* maskf = ws + 1 * NE;
    unsigned short* qf_g  = (unsigned short*)(ws + 2 * NE);   // frag-packed Q
    unsigned short* kf_g  = qf_g + NE;                        // frag-packed K
    unsigned short* h_bf  = kf_g + NE;
    unsigned short* wt    = h_bf + NE;
    const int WC = 3 * DD * DD;            // 196608
    const int WM = DD * DD;
    unsigned short* wtq0 = wt;
    unsigned short* wtq1 = wt + WC;
    unsigned short* wtk0 = wt + 2 * WC;
    unsigned short* wtk1 = wt + 3 * WC;
    unsigned short* wtv0 = wt + 4 * WC;
    unsigned short* wtv1 = wt + 5 * WC;
    unsigned short* wto1 = wt + 6 * WC;
    unsigned short* wto2 = wt + 6 * WC + WM;
    unsigned short* vf_g = wt + 6 * WC + 2 * WM;   // frag-packed V

    // fused: 8 weight slab-packs + LN1 + mask->float
    prep_kernel<<<1280 + T / 4 + 8, 256, 0, stream>>>(
        Wq, Wk, Wv, Wo1, Wo2, wt, x, ln1g, ln1b, h_bf, mask, maskf);

    // fused dual-layer temporal encoders (32-token tiles); frag-packed Q/K/V out
    convdual_kernel<<<(T / 32) * 3, 256, 0, stream>>>(
        h_bf, wtq0, wtk0, wtv0, wtq1, wtk1, wtv1, bq, bk, bv,
        qf_g, kf_g, vf_g, S);

    // MFMA attention, 2 q-frags/wave + block-shared LDS K/V -> attn (fp32)
    attn_mfma_kernel<<<BB * H * (S / 128), 256, 0, stream>>>(qf_g, kf_g, vf_g, maskf, attn, S, H);

    // fused tail: LN2 + MLP1 + GELU + MLP2 + residual -> out
    tail_kernel<<<T / 16, 256, 0, stream>>>(
        x, attn, ln2g, ln2b, wto1, bo1, wto2, bo2, out, S);
}

// Round 14
// 179.882 us; speedup vs baseline: 1.0647x; 1.0494x over previous
//
#include <hip/hip_runtime.h>
#include <hip/hip_bf16.h>
#include <math.h>

// Problem constants
#define BB 4
#define SS 2048
#define DD 256
#define HH 8
#define HSZ 32

typedef __attribute__((ext_vector_type(8))) short short8;   // 8 bf16 (4 VGPRs)
typedef __attribute__((ext_vector_type(4))) float f32x4;    // MFMA C/D frag

// Async global->LDS DMA, 16B per lane. LDS dest = wave-uniform base + lane*16;
// global src per-lane. Builtin (not asm) so compiler vmcnt bookkeeping sees it.
__device__ __forceinline__ void gload_lds16(const void* g, void* l) {
    __builtin_amdgcn_global_load_lds((const unsigned int*)g, (unsigned int*)l,
                                     16, 0, 0);
}

// Raw hardware exp2: one v_exp_f32 instead of OCML's ~8-op wrapped sequence.
__device__ __forceinline__ float exp2_hw(float x) {
    float r;
    asm("v_exp_f32 %0, %1" : "=v"(r) : "v"(x));
    return r;
}

// One-instruction bf16 pair pack: D = (a>>16) | (b & 0xffff0000)
__device__ __forceinline__ unsigned int perm_pack(float a, float b, unsigned int sel) {
    unsigned int r;
    asm("v_perm_b32 %0, %1, %2, %3"
        : "=v"(r)
        : "v"(__float_as_uint(b)), "v"(__float_as_uint(a)), "s"(sel));
    return r;
}

__device__ __forceinline__ float gelu_f(float x) {
    float x3 = x * x * x;
    float z = 0.7978845608028654f * fmaf(0.044715f, x3, x);
    float e = __expf(2.0f * z);
    float t = 1.0f - 2.0f / (e + 1.0f);
    return 0.5f * x * (1.0f + t);
}

__device__ __forceinline__ unsigned short f2bf(float f) {
    unsigned int u = __float_as_uint(f);
    u = (u + 0x7fffu + ((u >> 16) & 1u)) >> 16;
    return (unsigned short)u;
}

// ---------------- Wave-per-token LayerNorm body (no barriers) ----------------
template<bool HASRES>
__device__ __forceinline__ void ln_wave_body(
    int t, int lane,
    const float* __restrict__ x, const float* __restrict__ addin,
    const float* __restrict__ g, const float* __restrict__ bvec,
    float* __restrict__ resid_out, unsigned short* __restrict__ oln_bf)
{
    const int base = t * DD + lane * 4;
    float4 v4 = *(const float4*)&x[base];
    if (HASRES) {
        float4 a4 = *(const float4*)&addin[base];
        v4.x += a4.x; v4.y += a4.y; v4.z += a4.z; v4.w += a4.w;
        *(float4*)&resid_out[base] = v4;
    }
    float s = (v4.x + v4.y) + (v4.z + v4.w);
    #pragma unroll
    for (int o = 1; o < 64; o <<= 1) s += __shfl_xor(s, o);
    float mean = s * (1.0f / 256.0f);
    float dx = v4.x - mean, dy = v4.y - mean, dz = v4.z - mean, dw = v4.w - mean;
    float q = (dx * dx + dy * dy) + (dz * dz + dw * dw);
    #pragma unroll
    for (int o = 1; o < 64; o <<= 1) q += __shfl_xor(q, o);
    float r = rsqrtf(q * (1.0f / 256.0f) + 1e-6f);
    const float4 g4 = *(const float4*)&g[lane * 4];
    const float4 b4 = *(const float4*)&bvec[lane * 4];
    ushort4 o4;
    o4.x = f2bf(dx * r * g4.x + b4.x);
    o4.y = f2bf(dy * r * g4.y + b4.y);
    o4.z = f2bf(dz * r * g4.z + b4.z);
    o4.w = f2bf(dw * r * g4.w + b4.w);
    *(ushort4*)&oln_bf[base] = o4;
}

// ---------------- Fused prep: weight pack (0..1279) + LN1 (1280..3327) + maskf (3328..3335) ----------------
// Weight segments are written in SLAB-PACKED layout: the exact byte image
// the conv/tail LDS slab double-buffers consume, XOR-swizzle baked in:
//   element (och,k) -> slab s=k>>5, u = och*32+(k&31), u ^= ((u>>6)&7)<<3,
//   ushort index = s*8192 + u.
__global__ __launch_bounds__(256) void prep_kernel(
    const float* __restrict__ Wq, const float* __restrict__ Wk,
    const float* __restrict__ Wv, const float* __restrict__ Wo1,
    const float* __restrict__ Wo2, unsigned short* __restrict__ wt,
    const float* __restrict__ x, const float* __restrict__ ln1g,
    const float* __restrict__ ln1b, unsigned short* __restrict__ h_bf,
    const int* __restrict__ mask, float* __restrict__ maskf)
{
    if (blockIdx.x < 1280) {
        const int WCp = 3 * DD * DD;
        const int WMp = DD * DD;
        const float* src; unsigned short* dst; int rel;
        int i = blockIdx.x;
        if (i < 1152) {
            int seg = i / 192; rel = i % 192;
            src = seg == 0 ? Wq : seg == 1 ? Wq + WCp : seg == 2 ? Wk :
                  seg == 3 ? Wk + WCp : seg == 4 ? Wv : Wv + WCp;
            dst = wt + (size_t)seg * WCp;
        } else {
            int j = i - 1152; int seg = j / 64; rel = j % 64;
            src = seg == 0 ? Wo1 : Wo2;
            dst = wt + (size_t)6 * WCp + (size_t)seg * WMp;
        }
        __shared__ unsigned short t[32][33];
        const int tx = threadIdx.x & 31, ty = threadIdx.x >> 5;
        const int r0 = (rel / 8) * 32, c0 = (rel % 8) * 32;
        #pragma unroll
        for (int j = 0; j < 32; j += 8)
            t[ty + j][tx] = f2bf(src[(r0 + ty + j) * 256 + c0 + tx]);
        __syncthreads();
        #pragma unroll
        for (int j = 0; j < 32; j += 8) {
            unsigned int och = (unsigned int)(c0 + ty + j);
            unsigned int k   = (unsigned int)(r0 + tx);
            unsigned int u   = och * 32u + (k & 31u);
            u ^= ((u >> 6) & 7u) << 3;
            dst[(size_t)(k >> 5) * 8192 + u] = t[tx][ty + j];
        }
    } else if (blockIdx.x < 3328) {
        const int wv = threadIdx.x >> 6, lane = threadIdx.x & 63;
        ln_wave_body<false>((blockIdx.x - 1280) * 4 + wv, lane,
                            x, nullptr, ln1g, ln1b, nullptr, h_bf);
    } else {
        const float M_ON  = -8.0f * 1.4426950408889634f;
        const float M_OFF = -1.442695e30f;
        int i = (blockIdx.x - 3328) * 1024 + threadIdx.x * 4;
        int4 m4 = *(const int4*)&mask[i];
        float4 f4;
        f4.x = m4.x ? M_ON : M_OFF;
        f4.y = m4.y ? M_ON : M_OFF;
        f4.z = m4.z ? M_ON : M_OFF;
        f4.w = m4.w ? M_ON : M_OFF;
        *(float4*)&maskf[i] = f4;
    }
}

// ---------------- Fused dual-layer conv3, 32-token tiles, frag-layout outputs ----------------
// Slab-packed contiguous DMA (1KB/call) + rotated pipeline v2 (R9): per iter
//   lgkm(0) -> issue DMA(it+2) -> MFMA(it regs) -> vmcnt wait(it+1) -> ds_read(it+1)
__global__ __launch_bounds__(256, 3) void convdual_kernel(
    const unsigned short* __restrict__ in,
    const unsigned short* __restrict__ W0a, const unsigned short* __restrict__ W0b,
    const unsigned short* __restrict__ W0c,
    const unsigned short* __restrict__ W1a, const unsigned short* __restrict__ W1b,
    const unsigned short* __restrict__ W1c,
    const float* __restrict__ ba, const float* __restrict__ bb,
    const float* __restrict__ bc,
    unsigned short* __restrict__ oQ, unsigned short* __restrict__ oK,
    unsigned short* __restrict__ oV, int S)
{
    constexpr int LDW = 264;
    __shared__ __align__(16) unsigned short stage[36 * LDW];  // 19008B; aliased as inter + frag buffer
    __shared__ __align__(16) unsigned short wbuf[2][8192];    // 32768B slab double-buffer

    unsigned short* const inter = stage;   // alias: layer-1 output (34 rows x LDW)

    const int set = blockIdx.x % 3;
    const int tile = blockIdx.x / 3;
    const unsigned short* W0 = set == 0 ? W0a : (set == 1 ? W0b : W0c);
    const unsigned short* W1 = set == 0 ? W1a : (set == 1 ? W1b : W1c);
    const float* bias         = set == 0 ? ba  : (set == 1 ? bb  : bc);
    unsigned short* outp      = set == 0 ? oQ  : (set == 1 ? oK  : oV);

    const int tid = threadIdx.x;
    const int lane = tid & 63, wv = tid >> 6;
    const int lm = lane & 15, lq = lane >> 4;
    const int tpb = S / 32;
    const int b = tile / tpb;
    const int s0 = (tile % tpb) * 32;
    const int NC = S / 32;
    const int c = s0 >> 5;

    // stage tokens s0-2 .. s0+33 (rows 0..35)
    for (int i = tid; i < 36 * 32; i += 256) {
        int r = i >> 5, c8 = (i & 31) << 3;
        int s = s0 + r - 2;
        int4 val = make_int4(0, 0, 0, 0);
        if (s >= 0 && s < S)
            val = *(const int4*)&in[(size_t)(b * S + s) * 256 + c8];
        *(int4*)&stage[r * LDW + c8] = val;
    }

    const int n0 = wv * 64;

    // ---- weight-DMA addressing: contiguous per call ----
    const int wq = wv * 4096;                       // wave's quarter (bytes)
    const char* w0p = (const char*)W0 + wq + lane * 16;
    const char* w1p = (const char*)W1 + wq + lane * 16;
    char* const wb0 = (char*)wbuf;

    // B-frag ds_read offsets (swizzled), one per nt
    unsigned int boff[4];
    #pragma unroll
    for (int nt = 0; nt < 4; ++nt) {
        unsigned int och = (unsigned int)(n0 + nt * 16 + lm);
        unsigned int R = och * 64u + (unsigned int)lq * 16u;
        boff[nt] = R ^ (((R >> 7) & 7u) << 4);
    }

    __syncthreads();   // input stage visible; vm counters drained

    // ---- layer 1: rows j=0..33, 3 M-tiles, clamped halo on tile 2 ----
    {
        f32x4 acc[3][4];
        #pragma unroll
        for (int mt = 0; mt < 3; ++mt)
            #pragma unroll
            for (int nt = 0; nt < 4; ++nt) acc[mt][nt] = (f32x4){0.f, 0.f, 0.f, 0.f};

        // prologue: slab 0 -> buf0, slab 1 -> buf1
        #pragma unroll
        for (int j = 0; j < 4; ++j) gload_lds16(w0p + j * 1024,         wb0 + wq + j * 1024);
        #pragma unroll
        for (int j = 0; j < 4; ++j) gload_lds16(w0p + 16384 + j * 1024, wb0 + 16384 + wq + j * 1024);

        // A preload for it = 0
        short8 a0c, a1c, a2c;
        {
            const int icc0 = lq * 8;
            int r20 = 32 + lm; r20 = r20 > 35 ? 35 : r20;
            a0c = *(const short8*)&stage[lm * LDW + icc0];
            a1c = *(const short8*)&stage[(16 + lm) * LDW + icc0];
            a2c = *(const short8*)&stage[r20 * LDW + icc0];
        }

        asm volatile("s_waitcnt vmcnt(4)" ::: "memory");   // slab0 landed
        __builtin_amdgcn_sched_barrier(0);
        short8 bfc[4];
        #pragma unroll
        for (int nt = 0; nt < 4; ++nt)
            bfc[nt] = *(const short8*)(wb0 + boff[nt]);

        #pragma unroll
        for (int it = 0; it < 24; ++it) {
            asm volatile("s_waitcnt lgkmcnt(0)" ::: "memory");  // prior buf reads in regs
            __builtin_amdgcn_sched_barrier(0);
            if (it + 2 < 24) {   // issue slab it+2 into the buffer just consumed
                char* ld = wb0 + ((it & 1) << 14) + wq;
                const int soff = (it + 2) * 16384;
                #pragma unroll
                for (int j = 0; j < 4; ++j)
                    gload_lds16(w0p + soff + j * 1024, ld + j * 1024);
            }
            __builtin_amdgcn_sched_barrier(0);

            __builtin_amdgcn_s_setprio(1);
            #pragma unroll
            for (int nt = 0; nt < 4; ++nt) {
                acc[0][nt] = __builtin_amdgcn_mfma_f32_16x16x32_bf16(a0c, bfc[nt], acc[0][nt], 0, 0, 0);
                acc[1][nt] = __builtin_amdgcn_mfma_f32_16x16x32_bf16(a1c, bfc[nt], acc[1][nt], 0, 0, 0);
                acc[2][nt] = __builtin_amdgcn_mfma_f32_16x16x32_bf16(a2c, bfc[nt], acc[2][nt], 0, 0, 0);
            }
            __builtin_amdgcn_s_setprio(0);
            __builtin_amdgcn_sched_barrier(0);

            if (it + 1 < 24) {
                if (it + 2 < 24) { asm volatile("s_waitcnt vmcnt(4)" ::: "memory"); }
                else             { asm volatile("s_waitcnt vmcnt(0)" ::: "memory"); }
                __builtin_amdgcn_sched_barrier(0);
                const char* wb = wb0 + (((it + 1) & 1) << 14);
                #pragma unroll
                for (int nt = 0; nt < 4; ++nt)
                    bfc[nt] = *(const short8*)(wb + boff[nt]);
                const int kk = (it + 1) >> 3;
                const int icc = ((it + 1) & 7) * 32 + lq * 8;
                int r2 = kk + 32 + lm; r2 = r2 > 35 ? 35 : r2;  // clamped rows feed discarded outputs only
                a0c = *(const short8*)&stage[(kk + lm) * LDW + icc];
                a1c = *(const short8*)&stage[(kk + 16 + lm) * LDW + icc];
                a2c = *(const short8*)&stage[r2 * LDW + icc];
            }
        }

        __syncthreads();   // all waves done reading stage; safe to alias inter onto it

        // issue layer-2 slab 0/1 now; epilogue VALU below covers the DMA latency
        #pragma unroll
        for (int j = 0; j < 4; ++j) gload_lds16(w1p + j * 1024,         wb0 + wq + j * 1024);
        #pragma unroll
        for (int j = 0; j < 4; ++j) gload_lds16(w1p + 16384 + j * 1024, wb0 + 16384 + wq + j * 1024);

        #pragma unroll
        for (int mt = 0; mt < 3; ++mt)
            #pragma unroll
            for (int nt = 0; nt < 4; ++nt) {
                int ch = n0 + nt * 16 + lm;
                float bv = bias[ch];
                #pragma unroll
                for (int r = 0; r < 4; ++r) {
                    int j = mt * 16 + lq * 4 + r;
                    if (j < 34) {
                        int token = s0 - 1 + j;
                        unsigned short v = (token >= 0 && token < S)
                            ? f2bf(gelu_f(acc[mt][nt][r] + bv)) : (unsigned short)0;
                        inter[j * LDW + ch] = v;
                    }
                }
            }
    }
    __syncthreads();   // inter visible; slabs drained by the barrier's vm drain

    // ---- layer 2: rows m=0..31, 2 M-tiles, same rotated pipeline ----
    f32x4 acc2[2][4];
    #pragma unroll
    for (int mt = 0; mt < 2; ++mt)
        #pragma unroll
        for (int nt = 0; nt < 4; ++nt) acc2[mt][nt] = (f32x4){0.f, 0.f, 0.f, 0.f};
    {
        char* const wb0 = (char*)wbuf;
        // A preload for it = 0
        short8 a0c, a1c;
        {
            const int icc0 = lq * 8;
            a0c = *(const short8*)&inter[lm * LDW + icc0];
            a1c = *(const short8*)&inter[(16 + lm) * LDW + icc0];
        }

        asm volatile("s_waitcnt vmcnt(4)" ::: "memory");
        __builtin_amdgcn_sched_barrier(0);
        short8 bfc[4];
        #pragma unroll
        for (int nt = 0; nt < 4; ++nt)
            bfc[nt] = *(const short8*)(wb0 + boff[nt]);

        #pragma unroll
        for (int it = 0; it < 24; ++it) {
            asm volatile("s_waitcnt lgkmcnt(0)" ::: "memory");
            __builtin_amdgcn_sched_barrier(0);
            if (it + 2 < 24) {
                char* ld = wb0 + ((it & 1) << 14) + wq;
                const int soff = (it + 2) * 16384;
                #pragma unroll
                for (int j = 0; j < 4; ++j)
                    gload_lds16(w1p + soff + j * 1024, ld + j * 1024);
            }
            __builtin_amdgcn_sched_barrier(0);

            __builtin_amdgcn_s_setprio(1);
            #pragma unroll
            for (int nt = 0; nt < 4; ++nt) {
                acc2[0][nt] = __builtin_amdgcn_mfma_f32_16x16x32_bf16(a0c, bfc[nt], acc2[0][nt], 0, 0, 0);
                acc2[1][nt] = __builtin_amdgcn_mfma_f32_16x16x32_bf16(a1c, bfc[nt], acc2[1][nt], 0, 0, 0);
            }
            __builtin_amdgcn_s_setprio(0);
            __builtin_amdgcn_sched_barrier(0);

            if (it + 1 < 24) {
                if (it + 2 < 24) { asm volatile("s_waitcnt vmcnt(4)" ::: "memory"); }
                else             { asm volatile("s_waitcnt vmcnt(0)" ::: "memory"); }
                __builtin_amdgcn_sched_barrier(0);
                const char* wb = wb0 + (((it + 1) & 1) << 14);
                #pragma unroll
                for (int nt = 0; nt < 4; ++nt)
                    bfc[nt] = *(const short8*)(wb + boff[nt]);
                const int kk = (it + 1) >> 3;
                const int icc = ((it + 1) & 7) * 32 + lq * 8;
                a0c = *(const short8*)&inter[(kk + lm) * LDW + icc];
                a1c = *(const short8*)&inter[(kk + 16 + lm) * LDW + icc];
            }
        }
    }

    // ---- epilogue: frag-pack both halves into stage, coalesced writeout ----
    __syncthreads();   // all inter reads done; safe to overwrite stage
    if (set < 2) {
        #pragma unroll
        for (int mt = 0; mt < 2; ++mt)       // mt = half
            #pragma unroll
            for (int nt = 0; nt < 4; ++nt) {
                int o = n0 + nt * 16 + lm;
                int d = o & 31, h = o >> 5;
                float bv = bias[256 + o];
                #pragma unroll
                for (int r = 0; r < 4; ++r) {
                    int t = lq * 4 + r;
                    stage[mt * 4096 + (h * 64 + (d >> 3) * 16 + t) * 8 + (d & 7)] =
                        f2bf(acc2[mt][nt][r] + bv);
                }
            }
        __syncthreads();
        int h = tid >> 5;
        size_t base = ((size_t)(b * 8 + h) * NC + c) * 1024;
        #pragma unroll
        for (int half = 0; half < 2; ++half) {
            int4 v0 = *(const int4*)&stage[half * 4096 + tid * 16];
            int4 v1 = *(const int4*)&stage[half * 4096 + tid * 16 + 8];
            size_t dst = base + half * 512 + (tid & 31) * 16;
            *(int4*)&outp[dst] = v0;
            *(int4*)&outp[dst + 8] = v1;
        }
    } else {
        #pragma unroll
        for (int mt = 0; mt < 2; ++mt)
            #pragma unroll
            for (int nt = 0; nt < 4; ++nt) {
                int o = n0 + nt * 16 + lm;
                int d = o & 31, h = o >> 5;
                float bv = bias[256 + o];
                #pragma unroll
                for (int r = 0; r < 4; ++r) {
                    int t = lq * 4 + r;
                    stage[mt * 4096 +
                          ((h * 2 + (d >> 4)) * 32 + (t >> 3) * 16 + (d & 15)) * 8 + (t & 7)] =
                        f2bf(acc2[mt][nt][r] + bv);
                }
            }
        __syncthreads();
        int h = tid >> 5, dh = (tid >> 4) & 1;
        size_t base = ((size_t)(b * 8 + h) * NC + c) * 1024;
        #pragma unroll
        for (int half = 0; half < 2; ++half) {
            int4 v0 = *(const int4*)&stage[half * 4096 + tid * 16];
            int4 v1 = *(const int4*)&stage[half * 4096 + tid * 16 + 8];
            size_t dst = base + dh * 512 + half * 256 + (tid & 15) * 16;
            *(int4*)&outp[dst] = v0;
            *(int4*)&outp[dst + 8] = v1;
        }
    }
}

// ---------------- Fused tail: LN2 + MLP1(gelu) + MLP2 + residual ----------------
// Slab-packed contiguous DMA streaming; rotated pipeline v2 as in convdual.
__global__ __launch_bounds__(256, 2) void tail_kernel(
    const float* __restrict__ x, const float* __restrict__ attn,
    const float* __restrict__ g2, const float* __restrict__ b2,
    const unsigned short* __restrict__ W1, const float* __restrict__ bo1,
    const unsigned short* __restrict__ W2, const float* __restrict__ bo2,
    float* __restrict__ out, int S)
{
    constexpr int LDW = 264;
    __shared__ __align__(16) unsigned short h_lds[16 * LDW];
    __shared__ __align__(16) unsigned short h2_lds[16 * LDW];
    __shared__ __align__(16) float resid_lds[16][DD];
    __shared__ __align__(16) unsigned short wbuf[2][8192];    // 32KB slab dbuf

    const int tid = threadIdx.x;
    const int lane = tid & 63, wv = tid >> 6;
    const int lm = lane & 15, lq = lane >> 4;
    const int t0 = blockIdx.x * 16;
    const int n0 = wv * 64;

    const int wq = wv * 4096;
    const char* w1p = (const char*)W1 + wq + lane * 16;
    const char* w2p = (const char*)W2 + wq + lane * 16;
    char* const wb0 = (char*)wbuf;

    unsigned int boff[4];
    #pragma unroll
    for (int nt = 0; nt < 4; ++nt) {
        unsigned int och = (unsigned int)(n0 + nt * 16 + lm);
        unsigned int R = och * 64u + (unsigned int)lq * 16u;
        boff[nt] = R ^ (((R >> 7) & 7u) << 4);
    }

    // issue W1 slab 0/1 now; LN2 compute below covers the latency
    #pragma unroll
    for (int j = 0; j < 4; ++j) gload_lds16(w1p + j * 1024,         wb0 + wq + j * 1024);
    #pragma unroll
    for (int j = 0; j < 4; ++j) gload_lds16(w1p + 16384 + j * 1024, wb0 + 16384 + wq + j * 1024);

    #pragma unroll
    for (int j = 0; j < 4; ++j) {
        int t = wv * 4 + j;
        int base = (t0 + t) * DD + lane * 4;
        float4 v4 = *(const float4*)&x[base];
        float4 a4 = *(const float4*)&attn[base];
        v4.x += a4.x; v4.y += a4.y; v4.z += a4.z; v4.w += a4.w;
        *(float4*)&resid_lds[t][lane * 4] = v4;
        float s = (v4.x + v4.y) + (v4.z + v4.w);
        #pragma unroll
        for (int o = 1; o < 64; o <<= 1) s += __shfl_xor(s, o);
        float mean = s * (1.0f / 256.0f);
        float dx = v4.x - mean, dy = v4.y - mean, dz = v4.z - mean, dw = v4.w - mean;
        float q = (dx * dx + dy * dy) + (dz * dz + dw * dw);
        #pragma unroll
        for (int o = 1; o < 64; o <<= 1) q += __shfl_xor(q, o);
        float r = rsqrtf(q * (1.0f / 256.0f) + 1e-6f);
        const float4 g4 = *(const float4*)&g2[lane * 4];
        const float4 b4 = *(const float4*)&b2[lane * 4];
        ushort4 o4;
        o4.x = f2bf(dx * r * g4.x + b4.x);
        o4.y = f2bf(dy * r * g4.y + b4.y);
        o4.z = f2bf(dz * r * g4.z + b4.z);
        o4.w = f2bf(dw * r * g4.w + b4.w);
        *(ushort4*)&h_lds[t * LDW + lane * 4] = o4;
    }
    __syncthreads();

    {
        f32x4 acc[4];
        #pragma unroll
        for (int nt = 0; nt < 4; ++nt) acc[nt] = (f32x4){0.f, 0.f, 0.f, 0.f};

        short8 a0c = *(const short8*)&h_lds[lm * LDW + lq * 8];
        asm volatile("s_waitcnt vmcnt(4)" ::: "memory");
        __builtin_amdgcn_sched_barrier(0);
        short8 bfc[4];
        #pragma unroll
        for (int nt = 0; nt < 4; ++nt)
            bfc[nt] = *(const short8*)(wb0 + boff[nt]);

        #pragma unroll
        for (int it = 0; it < 8; ++it) {
            asm volatile("s_waitcnt lgkmcnt(0)" ::: "memory");
            __builtin_amdgcn_sched_barrier(0);
            if (it + 2 < 8) {
                char* ld = wb0 + ((it & 1) << 14) + wq;
                const int soff = (it + 2) * 16384;
                #pragma unroll
                for (int j = 0; j < 4; ++j)
                    gload_lds16(w1p + soff + j * 1024, ld + j * 1024);
            }
            __builtin_amdgcn_sched_barrier(0);

            __builtin_amdgcn_s_setprio(1);
            #pragma unroll
            for (int nt = 0; nt < 4; ++nt)
                acc[nt] = __builtin_amdgcn_mfma_f32_16x16x32_bf16(a0c, bfc[nt], acc[nt], 0, 0, 0);
            __builtin_amdgcn_s_setprio(0);
            __builtin_amdgcn_sched_barrier(0);

            if (it + 1 < 8) {
                if (it + 2 < 8) { asm volatile("s_waitcnt vmcnt(4)" ::: "memory"); }
                else            { asm volatile("s_waitcnt vmcnt(0)" ::: "memory"); }
                __builtin_amdgcn_sched_barrier(0);
                const char* wb = wb0 + (((it + 1) & 1) << 14);
                #pragma unroll
                for (int nt = 0; nt < 4; ++nt)
                    bfc[nt] = *(const short8*)(wb + boff[nt]);
                a0c = *(const short8*)&h_lds[lm * LDW + (it + 1) * 32 + lq * 8];
            }
        }

        // issue W2 slab 0/1; epilogue VALU below covers the latency
        asm volatile("s_waitcnt lgkmcnt(0)" ::: "memory");
        __builtin_amdgcn_sched_barrier(0);
        #pragma unroll
        for (int j = 0; j < 4; ++j) gload_lds16(w2p + j * 1024,         wb0 + wq + j * 1024);
        #pragma unroll
        for (int j = 0; j < 4; ++j) gload_lds16(w2p + 16384 + j * 1024, wb0 + 16384 + wq + j * 1024);

        #pragma unroll
        for (int nt = 0; nt < 4; ++nt) {
            int ch = n0 + nt * 16 + lm;
            float bv = bo1[ch];
            #pragma unroll
            for (int r = 0; r < 4; ++r) {
                int tok = lq * 4 + r;
                h2_lds[tok * LDW + ch] = f2bf(gelu_f(acc[nt][r] + bv));
            }
        }
    }
    __syncthreads();

    {
        f32x4 acc[4];
        #pragma unroll
        for (int nt = 0; nt < 4; ++nt) acc[nt] = (f32x4){0.f, 0.f, 0.f, 0.f};

        short8 a0c = *(const short8*)&h2_lds[lm * LDW + lq * 8];
        asm volatile("s_waitcnt vmcnt(4)" ::: "memory");
        __builtin_amdgcn_sched_barrier(0);
        short8 bfc[4];
        #pragma unroll
        for (int nt = 0; nt < 4; ++nt)
            bfc[nt] = *(const short8*)(wb0 + boff[nt]);

        #pragma unroll
        for (int it = 0; it < 8; ++it) {
            asm volatile("s_waitcnt lgkmcnt(0)" ::: "memory");
            __builtin_amdgcn_sched_barrier(0);
            if (it + 2 < 8) {
                char* ld = wb0 + ((it & 1) << 14) + wq;
                const int soff = (it + 2) * 16384;
                #pragma unroll
                for (int j = 0; j < 4; ++j)
                    gload_lds16(w2p + soff + j * 1024, ld + j * 1024);
            }
            __builtin_amdgcn_sched_barrier(0);

            __builtin_amdgcn_s_setprio(1);
            #pragma unroll
            for (int nt = 0; nt < 4; ++nt)
                acc[nt] = __builtin_amdgcn_mfma_f32_16x16x32_bf16(a0c, bfc[nt], acc[nt], 0, 0, 0);
            __builtin_amdgcn_s_setprio(0);
            __builtin_amdgcn_sched_barrier(0);

            if (it + 1 < 8) {
                if (it + 2 < 8) { asm volatile("s_waitcnt vmcnt(4)" ::: "memory"); }
                else            { asm volatile("s_waitcnt vmcnt(0)" ::: "memory"); }
                __builtin_amdgcn_sched_barrier(0);
                const char* wb = wb0 + (((it + 1) & 1) << 14);
                #pragma unroll
                for (int nt = 0; nt < 4; ++nt)
                    bfc[nt] = *(const short8*)(wb + boff[nt]);
                a0c = *(const short8*)&h2_lds[lm * LDW + (it + 1) * 32 + lq * 8];
            }
        }
        #pragma unroll
        for (int nt = 0; nt < 4; ++nt) {
            int ch = n0 + nt * 16 + lm;
            float bv = bo2[ch];
            #pragma unroll
            for (int r = 0; r < 4; ++r) {
                int tok = lq * 4 + r;
                out[(size_t)(t0 + tok) * DD + ch] = acc[nt][r] + bv + resid_lds[tok][ch];
            }
        }
    }
}

// ---------------- MFMA flash attention v11: 2 Q-frags per wave (half K/V traffic) ----------------
// Best measured attn config of the session (44.8us): 2 waves/SIMD, each wave
// owns 32 q-rows (both halves of one frag-packed Q chunk), amortizing each K/V
// chunk over 2x MFMA work. Ping-pong k/v register sets (no rotation movs);
// row-sum accumulated in the ones-MFMA C operand. Barrier-free.
__global__ __launch_bounds__(256) void attn_mfma_kernel(
    const unsigned short* __restrict__ Qf, const unsigned short* __restrict__ Kf,
    const unsigned short* __restrict__ Vf, const float* __restrict__ maskf,
    float* __restrict__ Out, int S, int H)
{
    constexpr int LDP = 40;
    __shared__ __align__(16) unsigned short p_lds[4][2][16 * LDP];

    const int bh = ((blockIdx.x & 7) << 2) | ((blockIdx.x >> 3) & 3);  // XCD locality
    const int qt = (blockIdx.x >> 5) * 128;
    const int b = bh / H;
    const int tid = threadIdx.x;
    const int lane = tid & 63, wv = tid >> 6;
    const int lm = lane & 15, lq = lane >> 4;
    const int q0 = qt + wv * 32;            // wave owns 32 q-rows
    const int NC = S / 32;                  // 64, even

    const size_t base = (size_t)bh * NC * 1024;
    const unsigned short* qp = &Qf[base + (size_t)(q0 >> 5) * 1024 + lane * 8];
    short8 qf0 = *(const short8*)(qp);       // rows q0..q0+15
    short8 qf1 = *(const short8*)(qp + 512); // rows q0+16..q0+31
    const unsigned short* kp = Kf + base + lane * 8;
    const unsigned short* vp = Vf + base + lane * 8;

    short8 ones;
    #pragma unroll
    for (int j = 0; j < 8; ++j) ones[j] = (short)0x3F80;  // bf16 1.0

    f32x4 o00 = {0.f, 0.f, 0.f, 0.f}, o01 = {0.f, 0.f, 0.f, 0.f};
    f32x4 o10 = {0.f, 0.f, 0.f, 0.f}, o11 = {0.f, 0.f, 0.f, 0.f};
    f32x4 lacc0 = {0.f, 0.f, 0.f, 0.f}, lacc1 = {0.f, 0.f, 0.f, 0.f};
    const f32x4 zf = {0.f, 0.f, 0.f, 0.f};

    const float scale2 = 0.17677669529663687f * 1.4426950408889634f;
    const unsigned int psel = 0x07060302u;   // v_perm selector, lives in SGPR
    const float* mp0 = maskf + b * S + lq * 4;
    const float* mp1 = mp0 + 16;

    unsigned short* pw0 = p_lds[wv][0];
    unsigned short* pw1 = p_lds[wv][1];
    const int pst = lm * LDP + lq * 4;
    const int prd = lm * LDP + lq * 8;

    // ping-pong register sets; A holds chunk 0 initially
    short8 kA0 = *(const short8*)(kp);
    short8 kA1 = *(const short8*)(kp + 512);
    short8 vA0 = *(const short8*)(vp);
    short8 vA1 = *(const short8*)(vp + 512);
    short8 kB0, kB1, vB0, vB1;

    for (int c = 0; c < NC; c += 2) {
        // prefetch chunk c+1 into B (NC even -> always valid)
        {
            const unsigned short* kq = kp + (size_t)(c + 1) * 1024;
            const unsigned short* vq = vp + (size_t)(c + 1) * 1024;
            kB0 = *(const short8*)(kq);
            kB1 = *(const short8*)(kq + 512);
            vB0 = *(const short8*)(vq);
            vB1 = *(const short8*)(vq + 512);
        }

        // ---- chunk c from A ----
        {
            f32x4 s00 = __builtin_amdgcn_mfma_f32_16x16x32_bf16(kA0, qf0, zf, 0, 0, 0);
            f32x4 s01 = __builtin_amdgcn_mfma_f32_16x16x32_bf16(kA1, qf0, zf, 0, 0, 0);
            f32x4 s10 = __builtin_amdgcn_mfma_f32_16x16x32_bf16(kA0, qf1, zf, 0, 0, 0);
            f32x4 s11 = __builtin_amdgcn_mfma_f32_16x16x32_bf16(kA1, qf1, zf, 0, 0, 0);

            float4 mf0 = *(const float4*)(mp0 + c * 32);
            float4 mf1 = *(const float4*)(mp1 + c * 32);

            float p0[8], p1[8];
            p0[0] = exp2_hw(fmaf(s00[0], scale2, mf0.x));
            p0[1] = exp2_hw(fmaf(s00[1], scale2, mf0.y));
            p0[2] = exp2_hw(fmaf(s00[2], scale2, mf0.z));
            p0[3] = exp2_hw(fmaf(s00[3], scale2, mf0.w));
            p0[4] = exp2_hw(fmaf(s01[0], scale2, mf1.x));
            p0[5] = exp2_hw(fmaf(s01[1], scale2, mf1.y));
            p0[6] = exp2_hw(fmaf(s01[2], scale2, mf1.z));
            p0[7] = exp2_hw(fmaf(s01[3], scale2, mf1.w));
            p1[0] = exp2_hw(fmaf(s10[0], scale2, mf0.x));
            p1[1] = exp2_hw(fmaf(s10[1], scale2, mf0.y));
            p1[2] = exp2_hw(fmaf(s10[2], scale2, mf0.z));
            p1[3] = exp2_hw(fmaf(s10[3], scale2, mf0.w));
            p1[4] = exp2_hw(fmaf(s11[0], scale2, mf1.x));
            p1[5] = exp2_hw(fmaf(s11[1], scale2, mf1.y));
            p1[6] = exp2_hw(fmaf(s11[2], scale2, mf1.z));
            p1[7] = exp2_hw(fmaf(s11[3], scale2, mf1.w));

            uint2 w0, w1;
            w0.x = perm_pack(p0[0], p0[1], psel); w0.y = perm_pack(p0[2], p0[3], psel);
            w1.x = perm_pack(p0[4], p0[5], psel); w1.y = perm_pack(p0[6], p0[7], psel);
            *(uint2*)&pw0[pst] = w0;
            *(uint2*)&pw0[pst + 16] = w1;
            w0.x = perm_pack(p1[0], p1[1], psel); w0.y = perm_pack(p1[2], p1[3], psel);
            w1.x = perm_pack(p1[4], p1[5], psel); w1.y = perm_pack(p1[6], p1[7], psel);
            *(uint2*)&pw1[pst] = w0;
            *(uint2*)&pw1[pst + 16] = w1;

            short8 pA0 = *(const short8*)&pw0[prd];   // wave-private, no barrier
            short8 pA1 = *(const short8*)&pw1[prd];

            lacc0 = __builtin_amdgcn_mfma_f32_16x16x32_bf16(pA0, ones, lacc0, 0, 0, 0);
            o00   = __builtin_amdgcn_mfma_f32_16x16x32_bf16(pA0, vA0, o00, 0, 0, 0);
            o01   = __builtin_amdgcn_mfma_f32_16x16x32_bf16(pA0, vA1, o01, 0, 0, 0);
            lacc1 = __builtin_amdgcn_mfma_f32_16x16x32_bf16(pA1, ones, lacc1, 0, 0, 0);
            o10   = __builtin_amdgcn_mfma_f32_16x16x32_bf16(pA1, vA0, o10, 0, 0, 0);
            o11   = __builtin_amdgcn_mfma_f32_16x16x32_bf16(pA1, vA1, o11, 0, 0, 0);
        }

        // prefetch chunk c+2 into A
        if (c + 2 < NC) {
            const unsigned short* kq = kp + (size_t)(c + 2) * 1024;
            const unsigned short* vq = vp + (size_t)(c + 2) * 1024;
            kA0 = *(const short8*)(kq);
            kA1 = *(const short8*)(kq + 512);
            vA0 = *(const short8*)(vq);
            vA1 = *(const short8*)(vq + 512);
        }

        // ---- chunk c+1 from B ----
        {
            f32x4 s00 = __builtin_amdgcn_mfma_f32_16x16x32_bf16(kB0, qf0, zf, 0, 0, 0);
            f32x4 s01 = __builtin_amdgcn_mfma_f32_16x16x32_bf16(kB1, qf0, zf, 0, 0, 0);
            f32x4 s10 = __builtin_amdgcn_mfma_f32_16x16x32_bf16(kB0, qf1, zf, 0, 0, 0);
            f32x4 s11 = __builtin_amdgcn_mfma_f32_16x16x32_bf16(kB1, qf1, zf, 0, 0, 0);

            float4 mf0 = *(const float4*)(mp0 + (c + 1) * 32);
            float4 mf1 = *(const float4*)(mp1 + (c + 1) * 32);

            float p0[8], p1[8];
            p0[0] = exp2_hw(fmaf(s00[0], scale2, mf0.x));
            p0[1] = exp2_hw(fmaf(s00[1], scale2, mf0.y));
            p0[2] = exp2_hw(fmaf(s00[2], scale2, mf0.z));
            p0[3] = exp2_hw(fmaf(s00[3], scale2, mf0.w));
            p0[4] = exp2_hw(fmaf(s01[0], scale2, mf1.x));
            p0[5] = exp2_hw(fmaf(s01[1], scale2, mf1.y));
            p0[6] = exp2_hw(fmaf(s01[2], scale2, mf1.z));
            p0[7] = exp2_hw(fmaf(s01[3], scale2, mf1.w));
            p1[0] = exp2_hw(fmaf(s10[0], scale2, mf0.x));
            p1[1] = exp2_hw(fmaf(s10[1], scale2, mf0.y));
            p1[2] = exp2_hw(fmaf(s10[2], scale2, mf0.z));
            p1[3] = exp2_hw(fmaf(s10[3], scale2, mf0.w));
            p1[4] = exp2_hw(fmaf(s11[0], scale2, mf1.x));
            p1[5] = exp2_hw(fmaf(s11[1], scale2, mf1.y));
            p1[6] = exp2_hw(fmaf(s11[2], scale2, mf1.z));
            p1[7] = exp2_hw(fmaf(s11[3], scale2, mf1.w));

            uint2 w0, w1;
            w0.x = perm_pack(p0[0], p0[1], psel); w0.y = perm_pack(p0[2], p0[3], psel);
            w1.x = perm_pack(p0[4], p0[5], psel); w1.y = perm_pack(p0[6], p0[7], psel);
            *(uint2*)&pw0[pst] = w0;
            *(uint2*)&pw0[pst + 16] = w1;
            w0.x = perm_pack(p1[0], p1[1], psel); w0.y = perm_pack(p1[2], p1[3], psel);
            w1.x = perm_pack(p1[4], p1[5], psel); w1.y = perm_pack(p1[6], p1[7], psel);
            *(uint2*)&pw1[pst] = w0;
            *(uint2*)&pw1[pst + 16] = w1;

            short8 pA0 = *(const short8*)&pw0[prd];
            short8 pA1 = *(const short8*)&pw1[prd];

            lacc0 = __builtin_amdgcn_mfma_f32_16x16x32_bf16(pA0, ones, lacc0, 0, 0, 0);
            o00   = __builtin_amdgcn_mfma_f32_16x16x32_bf16(pA0, vB0, o00, 0, 0, 0);
            o01   = __builtin_amdgcn_mfma_f32_16x16x32_bf16(pA0, vB1, o01, 0, 0, 0);
            lacc1 = __builtin_amdgcn_mfma_f32_16x16x32_bf16(pA1, ones, lacc1, 0, 0, 0);
            o10   = __builtin_amdgcn_mfma_f32_16x16x32_bf16(pA1, vB0, o10, 0, 0, 0);
            o11   = __builtin_amdgcn_mfma_f32_16x16x32_bf16(pA1, vB1, o11, 0, 0, 0);
        }
    }

    #pragma unroll
    for (int r = 0; r < 4; ++r) {
        float inv0 = 1.0f / lacc0[r];
        size_t ob0 = (size_t)(b * S + q0 + lq * 4 + r) * 256 + (bh % H) * 32;
        Out[ob0 + lm] = o00[r] * inv0;
        Out[ob0 + 16 + lm] = o01[r] * inv0;
        float inv1 = 1.0f / lacc1[r];
        size_t ob1 = (size_t)(b * S + q0 + 16 + lq * 4 + r) * 256 + (bh % H) * 32;
        Out[ob1 + lm] = o10[r] * inv1;
        Out[ob1 + 16 + lm] = o11[r] * inv1;
    }
}

extern "C" void kernel_launch(void* const* d_in, const int* in_sizes, int n_in,
                              void* d_out, int out_size, void* d_ws, size_t ws_size,
                              hipStream_t stream) {
    (void)in_sizes; (void)n_in; (void)out_size; (void)ws_size;
    const float* x    = (const float*)d_in[0];
    const float* ln1g = (const float*)d_in[1];
    const float* ln1b = (const float*)d_in[2];
    const float* Wq   = (const float*)d_in[3];
    const float* bq   = (const float*)d_in[4];
    const float* Wk   = (const float*)d_in[5];
    const float* bk   = (const float*)d_in[6];
    const float* Wv   = (const float*)d_in[7];
    const float* bv   = (const float*)d_in[8];
    const float* ln2g = (const float*)d_in[9];
    const float* ln2b = (const float*)d_in[10];
    const float* Wo1  = (const float*)d_in[11];
    const float* bo1  = (const float*)d_in[12];
    const float* Wo2  = (const float*)d_in[13];
    const float* bo2  = (const float*)d_in[14];
    const int*   mask = (const int*)d_in[15];
    float* out = (float*)d_out;

    const int S = SS, H = HH;
    const int T = BB * SS;                 // 8192 tokens
    const size_t NE = (size_t)T * DD;      // 2M elements
    float* ws    = (float*)d_ws;
    float* attn  = ws + 0 * NE;
    float* maskf = ws + 1 * NE;
    unsigned short* qf_g  = (unsigned short*)(ws + 2 * NE);   // frag-packed Q
    unsigned short* kf_g  = qf_g + NE;                        // frag-packed K
    unsigned short* h_bf  = kf_g + NE;
    unsigned short* wt    = h_bf + NE;
    const int WC = 3 * DD * DD;            // 196608
    const int WM = DD * DD;
    unsigned short* wtq0 = wt;
    unsigned short* wtq1 = wt + WC;
    unsigned short* wtk0 = wt + 2 * WC;
    unsigned short* wtk1 = wt + 3 * WC;
    unsigned short* wtv0 = wt + 4 * WC;
    unsigned short* wtv1 = wt + 5 * WC;
    unsigned short* wto1 = wt + 6 * WC;
    unsigned short* wto2 = wt + 6 * WC + WM;
    unsigned short* vf_g = wt + 6 * WC + 2 * WM;   // frag-packed V

    // fused: 8 weight slab-packs + LN1 + mask->float
    prep_kernel<<<1280 + T / 4 + 8, 256, 0, stream>>>(
        Wq, Wk, Wv, Wo1, Wo2, wt, x, ln1g, ln1b, h_bf, mask, maskf);

    // fused dual-layer temporal encoders (32-token tiles); frag-packed Q/K/V out
    convdual_kernel<<<(T / 32) * 3, 256, 0, stream>>>(
        h_bf, wtq0, wtk0, wtv0, wtq1, wtk1, wtv1, bq, bk, bv,
        qf_g, kf_g, vf_g, S);

    // barrier-free MFMA attention, 2 q-frags/wave -> attn (fp32)
    attn_mfma_kernel<<<BB * H * (S / 128), 256, 0, stream>>>(qf_g, kf_g, vf_g, maskf, attn, S, H);

    // fused tail: LN2 + MLP1 + GELU + MLP2 + residual -> out
    tail_kernel<<<T / 16, 256, 0, stream>>>(
        x, attn, ln2g, ln2b, wto1, bo1, wto2, bo2, out, S);
}